// Round 11
// baseline (683.202 us; speedup 1.0000x reference)
//
#include <hip/hip_runtime.h>

typedef unsigned short u16;
typedef __attribute__((ext_vector_type(8))) short s16x8;
typedef __attribute__((ext_vector_type(4))) float f32x4;

typedef __attribute__((address_space(3))) unsigned int lds_u32_t;
typedef __attribute__((address_space(1))) unsigned int glb_u32_t;

__device__ __forceinline__ float bf2f(u16 u) {
    union { unsigned int i; float f; } c; c.i = ((unsigned int)u) << 16; return c.f;
}
__device__ __forceinline__ u16 f2bf(float f) {
    union { float f; unsigned int u; } c; c.f = f;
    unsigned int u = c.u;
    unsigned int r = (u + 0x7fffu + ((u >> 16) & 1u)) >> 16;
    return (u16)r;
}
// async global->LDS, 16B/lane; dest = wave-uniform base + lane*16; global SRC is per-lane.
__device__ __forceinline__ void glds16(const u16* g, short* l) {
    __builtin_amdgcn_global_load_lds((glb_u32_t*)g, (lds_u32_t*)l, 16, 0, 0);
}

// ------------- transpose fp32 [R][C] -> bf16 hi/lo [C][R]  (Wq/Wk/Wv/Wo, split once) ---
__global__ __launch_bounds__(256) void transpose_split_kernel(const float* __restrict__ src,
                                                              u16* __restrict__ dh,
                                                              u16* __restrict__ dl,
                                                              int R, int C) {
    __shared__ float tile[32][33];
    int c0 = blockIdx.x * 32, r0 = blockIdx.y * 32;
    int tx = threadIdx.x & 31, ty = threadIdx.x >> 5;
    for (int i = 0; i < 4; i++)
        tile[ty + 8 * i][tx] = src[(size_t)(r0 + ty + 8 * i) * C + c0 + tx];
    __syncthreads();
    for (int i = 0; i < 4; i++) {
        float v = tile[tx][ty + 8 * i];
        u16 hb = f2bf(v);
        size_t idx = (size_t)(c0 + ty + 8 * i) * R + r0 + tx;
        dh[idx] = hb;
        dl[idx] = f2bf(v - bf2f(hb));
    }
}

// ------------- transpose fp32 [R][C] -> bf16 [C][R], blockIdx.z slice (W1/W2 -> [N][K]) -
__global__ __launch_bounds__(256) void transpose_f2b_kernel(const float* __restrict__ src,
                                                            u16* __restrict__ dst,
                                                            int R, int C) {
    __shared__ float tile[32][33];
    size_t zoff = (size_t)blockIdx.z * R * C;
    int c0 = blockIdx.x * 32, r0 = blockIdx.y * 32;
    int tx = threadIdx.x & 31, ty = threadIdx.x >> 5;
    for (int i = 0; i < 4; i++)
        tile[ty + 8 * i][tx] = src[zoff + (size_t)(r0 + ty + 8 * i) * C + c0 + tx];
    __syncthreads();
    for (int i = 0; i < 4; i++)
        dst[zoff + (size_t)(c0 + ty + 8 * i) * R + r0 + tx] = f2bf(tile[tx][ty + 8 * i]);
}

// ------------- layernorm fp32 -> bf16 hi/lo split (h1, split once) -------------
__global__ __launch_bounds__(256) void ln_split_kernel(const float* __restrict__ x,
                                                       const float* __restrict__ sc,
                                                       const float* __restrict__ bi,
                                                       u16* __restrict__ oh,
                                                       u16* __restrict__ ol) {
    int row = blockIdx.x, tid = threadIdx.x;
    f32x4 u = *(const f32x4*)(x + (size_t)row * 1024 + tid * 4);
    float s = u[0] + u[1] + u[2] + u[3];
    float ss = u[0]*u[0] + u[1]*u[1] + u[2]*u[2] + u[3]*u[3];
    for (int off = 1; off < 64; off <<= 1) { s += __shfl_xor(s, off, 64); ss += __shfl_xor(ss, off, 64); }
    __shared__ float red[8];
    if ((tid & 63) == 0) { red[tid >> 6] = s; red[4 + (tid >> 6)] = ss; }
    __syncthreads();
    s = red[0] + red[1] + red[2] + red[3];
    ss = red[4] + red[5] + red[6] + red[7];
    float mu = s * (1.0f / 1024.0f);
    float rstd = rsqrtf(ss * (1.0f / 1024.0f) - mu * mu + 1e-5f);
    f32x4 g = *(const f32x4*)(sc + tid * 4);
    f32x4 b = *(const f32x4*)(bi + tid * 4);
    size_t o = (size_t)row * 1024 + tid * 4;
    for (int i = 0; i < 4; i++) {
        float v = (u[i] - mu) * rstd * g[i] + b[i];
        u16 hb = f2bf(v);
        oh[o + i] = hb;
        ol[o + i] = f2bf(v - bf2f(hb));
    }
}

// ------------- layernorm fp32 -> bf16 (MoE GEMM input) -------------
__global__ __launch_bounds__(256) void ln_f2b_kernel(const float* __restrict__ x,
                                                     const float* __restrict__ sc,
                                                     const float* __restrict__ bi,
                                                     u16* __restrict__ out) {
    int row = blockIdx.x, tid = threadIdx.x;
    f32x4 u = *(const f32x4*)(x + (size_t)row * 1024 + tid * 4);
    float s = u[0] + u[1] + u[2] + u[3];
    float ss = u[0]*u[0] + u[1]*u[1] + u[2]*u[2] + u[3]*u[3];
    for (int off = 1; off < 64; off <<= 1) { s += __shfl_xor(s, off, 64); ss += __shfl_xor(ss, off, 64); }
    __shared__ float red[8];
    if ((tid & 63) == 0) { red[tid >> 6] = s; red[4 + (tid >> 6)] = ss; }
    __syncthreads();
    s = red[0] + red[1] + red[2] + red[3];
    ss = red[4] + red[5] + red[6] + red[7];
    float mu = s * (1.0f / 1024.0f);
    float rstd = rsqrtf(ss * (1.0f / 1024.0f) - mu * mu + 1e-5f);
    f32x4 g = *(const f32x4*)(sc + tid * 4);
    f32x4 b = *(const f32x4*)(bi + tid * 4);
    u16* op = out + (size_t)row * 1024 + tid * 4;
    for (int i = 0; i < 4; i++)
        op[i] = f2bf((u[i] - mu) * rstd * g[i] + b[i]);
}

// ------------- fused QKV GEMM: glds staging + static epilogue --------------------------
__global__ __launch_bounds__(256) void gemm3_qkv(const u16* __restrict__ Ah_g,
                                                 const u16* __restrict__ Al_g,
                                                 const u16* __restrict__ Bh_g,
                                                 const u16* __restrict__ Bl_g,
                                                 u16* __restrict__ Ch, u16* __restrict__ Cl,
                                                 float scale) {
    const int K = 1024;
    __shared__ __align__(16) short Ahs[128 * 32], Als[128 * 32];
    __shared__ __align__(16) short Bhs[128 * 32], Bls[128 * 32];
    int m0 = blockIdx.y * 128, n0 = blockIdx.x * 128;
    int tid = threadIdx.x, lane = tid & 63, w = tid >> 6;
    int wm = (w & 1) * 64, wn = (w >> 1) * 64;
    int lr = lane & 15, lq = lane >> 4;
    int r0 = w * 32 + (lane >> 2);
    int cv = (lane & 3) * 8;
    const u16* pAh = Ah_g + (size_t)(m0 + r0) * K + cv;
    const u16* pAl = Al_g + (size_t)(m0 + r0) * K + cv;
    const u16* pBh = Bh_g + (size_t)(n0 + r0) * K + cv;
    const u16* pBl = Bl_g + (size_t)(n0 + r0) * K + cv;
    size_t st16 = (size_t)16 * K;
    f32x4 acc[4][4] = {};

    for (int k0 = 0; k0 < K; k0 += 32) {
        glds16(pAh + k0, &Ahs[w * 1024]);  glds16(pAh + k0 + st16, &Ahs[w * 1024 + 512]);
        glds16(pAl + k0, &Als[w * 1024]);  glds16(pAl + k0 + st16, &Als[w * 1024 + 512]);
        glds16(pBh + k0, &Bhs[w * 1024]);  glds16(pBh + k0 + st16, &Bhs[w * 1024 + 512]);
        glds16(pBl + k0, &Bls[w * 1024]);  glds16(pBl + k0 + st16, &Bls[w * 1024 + 512]);
        __syncthreads();   // barrier drains vmcnt: glds writes visible
        s16x8 ah[4], al[4], bh[4], bl[4];
        #pragma unroll
        for (int i = 0; i < 4; i++) {
            int off = (wm + i * 16 + lr) * 32 + lq * 8;
            ah[i] = *(const s16x8*)&Ahs[off];
            al[i] = *(const s16x8*)&Als[off];
        }
        #pragma unroll
        for (int j = 0; j < 4; j++) {
            int off = (wn + j * 16 + lr) * 32 + lq * 8;
            bh[j] = *(const s16x8*)&Bhs[off];
            bl[j] = *(const s16x8*)&Bls[off];
        }
        #pragma unroll
        for (int i = 0; i < 4; i++)
            #pragma unroll
            for (int j = 0; j < 4; j++) {
                acc[i][j] = __builtin_amdgcn_mfma_f32_16x16x32_bf16(al[i], bh[j], acc[i][j], 0, 0, 0);
                acc[i][j] = __builtin_amdgcn_mfma_f32_16x16x32_bf16(ah[i], bl[j], acc[i][j], 0, 0, 0);
                acc[i][j] = __builtin_amdgcn_mfma_f32_16x16x32_bf16(ah[i], bh[j], acc[i][j], 0, 0, 0);
            }
        __syncthreads();
    }

    int seg = n0 >> 10;
    float sc = (seg == 0) ? scale : 1.0f;
    u16* Chp = Ch + (size_t)seg * 8388608;
    u16* Clp = Cl + (size_t)seg * 8388608;
    int c0 = (n0 & 1023) + wn;
    #pragma unroll
    for (int i = 0; i < 4; i++)
        #pragma unroll
        for (int j = 0; j < 4; j++)
            #pragma unroll
            for (int r = 0; r < 4; r++) {
                int row = m0 + wm + i * 16 + lq * 4 + r;
                int col = c0 + j * 16 + lr;
                float vv = acc[i][j][r] * sc;
                u16 hb = f2bf(vv);
                u16 lb = f2bf(vv - bf2f(hb));
                size_t idx = (size_t)row * 1024 + col;
                Chp[idx] = hb; Clp[idx] = lb;
            }
}

// ------------- Wo GEMM: glds staging, fp32 C = A@B^T + res ----------------------------
__global__ __launch_bounds__(256) void gemm3_res(const u16* __restrict__ Ah_g,
                                                 const u16* __restrict__ Al_g,
                                                 const u16* __restrict__ Bh_g,
                                                 const u16* __restrict__ Bl_g,
                                                 float* __restrict__ C,
                                                 const float* __restrict__ res) {
    const int K = 1024, N = 1024;
    __shared__ __align__(16) short Ahs[128 * 32], Als[128 * 32];
    __shared__ __align__(16) short Bhs[128 * 32], Bls[128 * 32];
    int m0 = blockIdx.y * 128, n0 = blockIdx.x * 128;
    int tid = threadIdx.x, lane = tid & 63, w = tid >> 6;
    int wm = (w & 1) * 64, wn = (w >> 1) * 64;
    int lr = lane & 15, lq = lane >> 4;
    int r0 = w * 32 + (lane >> 2);
    int cv = (lane & 3) * 8;
    const u16* pAh = Ah_g + (size_t)(m0 + r0) * K + cv;
    const u16* pAl = Al_g + (size_t)(m0 + r0) * K + cv;
    const u16* pBh = Bh_g + (size_t)(n0 + r0) * K + cv;
    const u16* pBl = Bl_g + (size_t)(n0 + r0) * K + cv;
    size_t st16 = (size_t)16 * K;
    f32x4 acc[4][4] = {};

    for (int k0 = 0; k0 < K; k0 += 32) {
        glds16(pAh + k0, &Ahs[w * 1024]);  glds16(pAh + k0 + st16, &Ahs[w * 1024 + 512]);
        glds16(pAl + k0, &Als[w * 1024]);  glds16(pAl + k0 + st16, &Als[w * 1024 + 512]);
        glds16(pBh + k0, &Bhs[w * 1024]);  glds16(pBh + k0 + st16, &Bhs[w * 1024 + 512]);
        glds16(pBl + k0, &Bls[w * 1024]);  glds16(pBl + k0 + st16, &Bls[w * 1024 + 512]);
        __syncthreads();
        s16x8 ah[4], al[4], bh[4], bl[4];
        #pragma unroll
        for (int i = 0; i < 4; i++) {
            int off = (wm + i * 16 + lr) * 32 + lq * 8;
            ah[i] = *(const s16x8*)&Ahs[off];
            al[i] = *(const s16x8*)&Als[off];
        }
        #pragma unroll
        for (int j = 0; j < 4; j++) {
            int off = (wn + j * 16 + lr) * 32 + lq * 8;
            bh[j] = *(const s16x8*)&Bhs[off];
            bl[j] = *(const s16x8*)&Bls[off];
        }
        #pragma unroll
        for (int i = 0; i < 4; i++)
            #pragma unroll
            for (int j = 0; j < 4; j++) {
                acc[i][j] = __builtin_amdgcn_mfma_f32_16x16x32_bf16(al[i], bh[j], acc[i][j], 0, 0, 0);
                acc[i][j] = __builtin_amdgcn_mfma_f32_16x16x32_bf16(ah[i], bl[j], acc[i][j], 0, 0, 0);
                acc[i][j] = __builtin_amdgcn_mfma_f32_16x16x32_bf16(ah[i], bh[j], acc[i][j], 0, 0, 0);
            }
        __syncthreads();
    }

    #pragma unroll
    for (int i = 0; i < 4; i++)
        #pragma unroll
        for (int j = 0; j < 4; j++)
            #pragma unroll
            for (int r = 0; r < 4; r++) {
                int row = m0 + wm + i * 16 + lq * 4 + r;
                int col = n0 + wn + j * 16 + lr;
                size_t idx = (size_t)row * N + col;
                C[idx] = acc[i][j][r] + res[idx];
            }
}

// ------------- init out = x2 (before sparse MoE down atomically accumulates) ----------
__global__ __launch_bounds__(256) void init_out_kernel(const float* __restrict__ x2,
                                                       float* __restrict__ out) {
    size_t i = ((size_t)blockIdx.x * 256 + threadIdx.x) * 4;
    *(f32x4*)(out + i) = *(const f32x4*)(x2 + i);
}

// ------------- sparse MoE up: per-expert gathered GEMM --------------------------------
// grid (2, 80). Row-tiles enumerate (expert, 128-pair tile) via cnt[] prefix scan.
// A rows gathered from h2 by token list (per-lane glds source). Per-row math is
// BIT-IDENTICAL to the dense version (same K-order, same B rows, same relu*gate*f2bf).
__global__ __launch_bounds__(256) void gemm_moe_up_sparse(const u16* __restrict__ h2,
                                                          const u16* __restrict__ W1T,
                                                          const int* __restrict__ cnt,
                                                          const int* __restrict__ list,
                                                          const float* __restrict__ gates,
                                                          u16* __restrict__ up_buf) {
    const int K = 1024;
    __shared__ __align__(16) short As[128 * 32];
    __shared__ __align__(16) short Bs[128 * 32];
    int e = -1, tstart = 0;
    {
        int ty = blockIdx.y, at = 0;
        for (int i = 0; i < 16; i++) {
            int nt = (cnt[i] + 127) >> 7;
            if (ty < at + nt) { e = i; tstart = (ty - at) * 128; break; }
            at += nt;
        }
    }
    if (e < 0) return;
    int ncnt = cnt[e];
    int n0 = blockIdx.x * 128;
    int tid = threadIdx.x, lane = tid & 63, w = tid >> 6;
    int wm = (w & 1) * 64, wn = (w >> 1) * 64;
    int lr = lane & 15, lq = lane >> 4;
    int r0 = w * 32 + (lane >> 2);
    int cv = (lane & 3) * 8;
    int p0 = tstart + r0, p1 = tstart + r0 + 16;
    int t0 = list[e * 4096 + (p0 < ncnt ? p0 : ncnt - 1)];
    int t1 = list[e * 4096 + (p1 < ncnt ? p1 : ncnt - 1)];
    const u16* pA0 = h2 + (size_t)t0 * K + cv;
    const u16* pA1 = h2 + (size_t)t1 * K + cv;
    const u16* pB  = W1T + (size_t)(e * 256 + n0 + r0) * K + cv;
    size_t st16 = (size_t)16 * K;
    f32x4 acc[4][4] = {};

    for (int k0 = 0; k0 < K; k0 += 32) {
        glds16(pA0 + k0, &As[w * 1024]);  glds16(pA1 + k0, &As[w * 1024 + 512]);
        glds16(pB + k0, &Bs[w * 1024]);   glds16(pB + k0 + st16, &Bs[w * 1024 + 512]);
        __syncthreads();
        s16x8 av[4], bv[4];
        #pragma unroll
        for (int i = 0; i < 4; i++) av[i] = *(const s16x8*)&As[(wm + i * 16 + lr) * 32 + lq * 8];
        #pragma unroll
        for (int j = 0; j < 4; j++) bv[j] = *(const s16x8*)&Bs[(wn + j * 16 + lr) * 32 + lq * 8];
        #pragma unroll
        for (int i = 0; i < 4; i++)
            #pragma unroll
            for (int j = 0; j < 4; j++)
                acc[i][j] = __builtin_amdgcn_mfma_f32_16x16x32_bf16(av[i], bv[j], acc[i][j], 0, 0, 0);
        __syncthreads();
    }

    #pragma unroll
    for (int i = 0; i < 4; i++)
        #pragma unroll
        for (int j = 0; j < 4; j++)
            #pragma unroll
            for (int r = 0; r < 4; r++) {
                int rl = wm + i * 16 + lq * 4 + r;
                int p = tstart + rl;
                if (p < ncnt) {
                    int t = list[e * 4096 + p];
                    float g = gates[(size_t)t * 16 + e];
                    int col = n0 + wn + j * 16 + lr;
                    up_buf[(size_t)(e * 4096 + p) * 256 + col] = f2bf(fmaxf(acc[i][j][r], 0.0f) * g);
                }
            }
}

// ------------- sparse MoE down: per-expert GEMM (K=256), atomicAdd into out -----------
// grid (8, 80). out pre-initialized to x2; each (token,d) receives exactly 2 atomic
// contributions (its two experts). Output-only rounding change -- no router dependency.
__global__ __launch_bounds__(256) void gemm_moe_down_sparse(const u16* __restrict__ up_buf,
                                                            const u16* __restrict__ W2T,
                                                            const int* __restrict__ cnt,
                                                            const int* __restrict__ list,
                                                            float* __restrict__ out) {
    const int K = 256;
    __shared__ __align__(16) short As[128 * 32];
    __shared__ __align__(16) short Bs[128 * 32];
    int e = -1, tstart = 0;
    {
        int ty = blockIdx.y, at = 0;
        for (int i = 0; i < 16; i++) {
            int nt = (cnt[i] + 127) >> 7;
            if (ty < at + nt) { e = i; tstart = (ty - at) * 128; break; }
            at += nt;
        }
    }
    if (e < 0) return;
    int ncnt = cnt[e];
    int n0 = blockIdx.x * 128;
    int tid = threadIdx.x, lane = tid & 63, w = tid >> 6;
    int wm = (w & 1) * 64, wn = (w >> 1) * 64;
    int lr = lane & 15, lq = lane >> 4;
    int r0 = w * 32 + (lane >> 2);
    int cv = (lane & 3) * 8;
    int p0 = tstart + r0, p1 = tstart + r0 + 16;
    int pc0 = p0 < ncnt ? p0 : ncnt - 1;
    int pc1 = p1 < ncnt ? p1 : ncnt - 1;
    const u16* pA0 = up_buf + (size_t)(e * 4096 + pc0) * 256 + cv;
    const u16* pA1 = up_buf + (size_t)(e * 4096 + pc1) * 256 + cv;
    const u16* pB  = W2T + (size_t)(n0 + r0) * 4096 + e * 256 + cv;
    size_t st16 = (size_t)16 * 4096;
    f32x4 acc[4][4] = {};

    for (int k0 = 0; k0 < K; k0 += 32) {
        glds16(pA0 + k0, &As[w * 1024]);  glds16(pA1 + k0, &As[w * 1024 + 512]);
        glds16(pB + k0, &Bs[w * 1024]);   glds16(pB + k0 + st16, &Bs[w * 1024 + 512]);
        __syncthreads();
        s16x8 av[4], bv[4];
        #pragma unroll
        for (int i = 0; i < 4; i++) av[i] = *(const s16x8*)&As[(wm + i * 16 + lr) * 32 + lq * 8];
        #pragma unroll
        for (int j = 0; j < 4; j++) bv[j] = *(const s16x8*)&Bs[(wn + j * 16 + lr) * 32 + lq * 8];
        #pragma unroll
        for (int i = 0; i < 4; i++)
            #pragma unroll
            for (int j = 0; j < 4; j++)
                acc[i][j] = __builtin_amdgcn_mfma_f32_16x16x32_bf16(av[i], bv[j], acc[i][j], 0, 0, 0);
        __syncthreads();
    }

    #pragma unroll
    for (int i = 0; i < 4; i++)
        #pragma unroll
        for (int j = 0; j < 4; j++)
            #pragma unroll
            for (int r = 0; r < 4; r++) {
                int rl = wm + i * 16 + lq * 4 + r;
                int p = tstart + rl;
                if (p < ncnt) {
                    int t = list[e * 4096 + p];
                    int col = n0 + wn + j * 16 + lr;
                    atomicAdd(&out[(size_t)t * 1024 + col], acc[i][j][r]);
                }
            }
}

// ------------- V transpose: v_hi/lo [4096][1024] -> vT_hi/lo [32 bh][64 d][2048 s] -------
__global__ __launch_bounds__(256) void vtrans_kernel(const u16* __restrict__ v_hi,
                                                     const u16* __restrict__ v_lo,
                                                     u16* __restrict__ vT_hi,
                                                     u16* __restrict__ vT_lo) {
    __shared__ __align__(16) short tile[64][72];
    int st = blockIdx.x, bh = blockIdx.y;
    int b = bh >> 4, h = bh & 15;
    int tid = threadIdx.x;
    int i = tid >> 2, seg = (tid & 3) * 16;
    for (int p = 0; p < 2; p++) {
        const u16* src = p ? v_lo : v_hi;
        u16* dst = p ? vT_lo : vT_hi;
        size_t goff = (size_t)(b * 2048 + st * 64 + i) * 1024 + h * 64 + seg;
        *(s16x8*)&tile[i][seg]     = *(const s16x8*)&src[goff];
        *(s16x8*)&tile[i][seg + 8] = *(const s16x8*)&src[goff + 8];
        __syncthreads();
        s16x8 o0, o1;
        for (int j = 0; j < 8; j++) { o0[j] = tile[seg + j][i]; o1[j] = tile[seg + 8 + j][i]; }
        size_t doff = ((size_t)bh * 64 + i) * 2048 + st * 64 + seg;
        *(s16x8*)&dst[doff]     = o0;
        *(s16x8*)&dst[doff + 8] = o1;
        __syncthreads();
    }
}

// ------------- MFMA flash attention, split-bf16 (3-term), online softmax -------------
// EXACT round-9 kernel (205us measured): 128-row blocks, rt loop, XCD swizzle,
// swizzled P buffer [16*64] (idx ^= (row&7)<<3 both sides), Ph+Pl 3-term PV.
// Round-10's 64-row variant regressed (doubled staging:compute) -- reverted.
__global__ __launch_bounds__(256) void attn_mfma(const u16* __restrict__ qh_g,
                                                 const u16* __restrict__ ql_g,
                                                 const u16* __restrict__ kh_g,
                                                 const u16* __restrict__ kl_g,
                                                 const u16* __restrict__ vth_g,
                                                 const u16* __restrict__ vtl_g,
                                                 u16* __restrict__ ch_g,
                                                 u16* __restrict__ cl_g) {
    __shared__ __align__(16) short Ksh[64][72], Ksl[64][72], Vsh[64][72], Vsl[64][72];
    __shared__ __align__(16) short Ph[4][16 * 64], Pl[4][16 * 64];
    int lin = blockIdx.x + 16 * blockIdx.y;
    int xcd = lin & 7, rest = lin >> 3;
    int qt = rest & 15;
    int bh = xcd + 8 * (rest >> 4);
    int b = bh >> 4, h = bh & 15;
    int tid = threadIdx.x, w = tid >> 6, lane = tid & 63;
    int lr = lane & 15, lq = lane >> 4;
    int qbase = qt * 128 + w * 32;

    s16x8 qfh[2][2], qfl[2][2];
    for (int rt = 0; rt < 2; rt++)
        for (int kc = 0; kc < 2; kc++) {
            size_t qoff = (size_t)(b * 2048 + qbase + rt * 16 + lr) * 1024 + h * 64 + kc * 32 + lq * 8;
            qfh[rt][kc] = *(const s16x8*)&qh_g[qoff];
            qfl[rt][kc] = *(const s16x8*)&ql_g[qoff];
        }

    float m_[2][4], l_[2][4];
    f32x4 O[2][4] = {};
    for (int rt = 0; rt < 2; rt++)
        for (int r = 0; r < 4; r++) { m_[rt][r] = -1e30f; l_[rt][r] = 0.0f; }

    for (int kc0 = 0; kc0 < 2048; kc0 += 64) {
        {   // stage K chunk [key][d] and V^T chunk [d][key] (L2-hits after swizzle)
            int kk = tid >> 2, seg = (tid & 3) * 16;
            size_t goff = (size_t)(b * 2048 + kc0 + kk) * 1024 + h * 64 + seg;
            *(s16x8*)&Ksh[kk][seg]     = *(const s16x8*)&kh_g[goff];
            *(s16x8*)&Ksh[kk][seg + 8] = *(const s16x8*)&kh_g[goff + 8];
            *(s16x8*)&Ksl[kk][seg]     = *(const s16x8*)&kl_g[goff];
            *(s16x8*)&Ksl[kk][seg + 8] = *(const s16x8*)&kl_g[goff + 8];
            size_t voff = ((size_t)bh * 64 + kk) * 2048 + kc0 + seg;
            *(s16x8*)&Vsh[kk][seg]     = *(const s16x8*)&vth_g[voff];
            *(s16x8*)&Vsh[kk][seg + 8] = *(const s16x8*)&vth_g[voff + 8];
            *(s16x8*)&Vsl[kk][seg]     = *(const s16x8*)&vtl_g[voff];
            *(s16x8*)&Vsl[kk][seg + 8] = *(const s16x8*)&vtl_g[voff + 8];
        }
        __syncthreads();

        f32x4 s[2][4] = {};
        for (int ct = 0; ct < 4; ct++)
            for (int kc = 0; kc < 2; kc++) {
                s16x8 kbh = *(const s16x8*)&Ksh[ct * 16 + lr][kc * 32 + lq * 8];
                s16x8 kbl = *(const s16x8*)&Ksl[ct * 16 + lr][kc * 32 + lq * 8];
                for (int rt = 0; rt < 2; rt++) {
                    s[rt][ct] = __builtin_amdgcn_mfma_f32_16x16x32_bf16(qfl[rt][kc], kbh, s[rt][ct], 0, 0, 0);
                    s[rt][ct] = __builtin_amdgcn_mfma_f32_16x16x32_bf16(qfh[rt][kc], kbl, s[rt][ct], 0, 0, 0);
                    s[rt][ct] = __builtin_amdgcn_mfma_f32_16x16x32_bf16(qfh[rt][kc], kbh, s[rt][ct], 0, 0, 0);
                }
            }

        for (int rt = 0; rt < 2; rt++) {
            float al[4];
            for (int ri = 0; ri < 4; ri++) {
                float mx = fmaxf(fmaxf(s[rt][0][ri], s[rt][1][ri]), fmaxf(s[rt][2][ri], s[rt][3][ri]));
                for (int off = 1; off < 16; off <<= 1) mx = fmaxf(mx, __shfl_xor(mx, off, 64));
                float mn = fmaxf(m_[rt][ri], mx);
                float a = __expf(m_[rt][ri] - mn);
                m_[rt][ri] = mn; al[ri] = a;
                float ps = 0.0f;
                for (int ct = 0; ct < 4; ct++) {
                    float p = __expf(s[rt][ct][ri] - mn);
                    s[rt][ct][ri] = p; ps += p;
                }
                for (int off = 1; off < 16; off <<= 1) ps += __shfl_xor(ps, off, 64);
                l_[rt][ri] = l_[rt][ri] * a + ps;
            }
            for (int nt = 0; nt < 4; nt++)
                for (int ri = 0; ri < 4; ri++) O[rt][nt][ri] *= al[ri];
            for (int ct = 0; ct < 4; ct++)
                for (int ri = 0; ri < 4; ri++) {
                    float p = s[rt][ct][ri];
                    u16 hb = f2bf(p);
                    u16 lb = f2bf(p - bf2f(hb));
                    int row = lq * 4 + ri, col = ct * 16 + lr;
                    int pidx = (row * 64 + col) ^ ((row & 7) << 3);
                    Ph[w][pidx] = (short)hb;
                    Pl[w][pidx] = (short)lb;
                }
            asm volatile("s_waitcnt lgkmcnt(0)" ::: "memory");
            __builtin_amdgcn_sched_barrier(0);
            __builtin_amdgcn_s_setprio(1);
            for (int kc = 0; kc < 2; kc++) {
                int pidx = (lr * 64 + kc * 32 + lq * 8) ^ ((lr & 7) << 3);
                s16x8 pah = *(const s16x8*)&Ph[w][pidx];
                s16x8 pal = *(const s16x8*)&Pl[w][pidx];
                for (int nt = 0; nt < 4; nt++) {
                    s16x8 vbh = *(const s16x8*)&Vsh[nt * 16 + lr][kc * 32 + lq * 8];
                    s16x8 vbl = *(const s16x8*)&Vsl[nt * 16 + lr][kc * 32 + lq * 8];
                    O[rt][nt] = __builtin_amdgcn_mfma_f32_16x16x32_bf16(pal, vbh, O[rt][nt], 0, 0, 0);
                    O[rt][nt] = __builtin_amdgcn_mfma_f32_16x16x32_bf16(pah, vbl, O[rt][nt], 0, 0, 0);
                    O[rt][nt] = __builtin_amdgcn_mfma_f32_16x16x32_bf16(pah, vbh, O[rt][nt], 0, 0, 0);
                }
            }
            __builtin_amdgcn_s_setprio(0);
            asm volatile("s_waitcnt lgkmcnt(0)" ::: "memory");
            __builtin_amdgcn_sched_barrier(0);
        }
        __syncthreads();
    }

    for (int rt = 0; rt < 2; rt++)
        for (int nt = 0; nt < 4; nt++)
            for (int ri = 0; ri < 4; ri++) {
                int row = qbase + rt * 16 + lq * 4 + ri;
                int d = nt * 16 + lr;
                float v = O[rt][nt][ri] / l_[rt][ri];
                u16 hb = f2bf(v);
                size_t idx = (size_t)(b * 2048 + row) * 1024 + h * 64 + d;
                ch_g[idx] = hb;
                cl_g[idx] = f2bf(v - bf2f(hb));
            }
}

// ------------- router: pure fp32 + expert token-list build ----------------------------
__global__ __launch_bounds__(256) void router_kernel(const float* __restrict__ x2,
                                                     const float* __restrict__ sc,
                                                     const float* __restrict__ bi,
                                                     const float* __restrict__ Wsel,
                                                     float* __restrict__ gates,
                                                     int* __restrict__ cnt,
                                                     int* __restrict__ list) {
    int tid = threadIdx.x, w = tid >> 6, lane = tid & 63;
    int t = blockIdx.x * 4 + w;
    const float* xp = x2 + (size_t)t * 1024;
    float s = 0.0f, ss = 0.0f;
    for (int i = 0; i < 16; i++) {
        float v = xp[lane * 16 + i];
        s += v; ss += v * v;
    }
    for (int off = 1; off < 64; off <<= 1) { s += __shfl_xor(s, off, 64); ss += __shfl_xor(ss, off, 64); }
    float mu = s * (1.0f / 1024.0f);
    float rstd = rsqrtf(ss * (1.0f / 1024.0f) - mu * mu + 1e-5f);
    int e = lane & 15, part = lane >> 4;
    float acc = 0.0f;
    for (int d = part * 256; d < part * 256 + 256; d++) {
        float h = (xp[d] - mu) * rstd * sc[d] + bi[d];
        acc += h * Wsel[(size_t)d * 16 + e];
    }
    acc += __shfl_xor(acc, 16, 64);
    acc += __shfl_xor(acc, 32, 64);
    float v = 1.0f / (1.0f + __expf(-acc));
    float m1 = v;
    for (int off = 1; off < 64; off <<= 1) m1 = fmaxf(m1, __shfl_xor(m1, off, 64));
    unsigned long long b1 = __ballot(v == m1);
    int e1 = (__ffsll(b1) - 1) & 15;
    float v2 = (e == e1) ? -1e30f : v;
    float m2 = v2;
    for (int off = 1; off < 64; off <<= 1) m2 = fmaxf(m2, __shfl_xor(m2, off, 64));
    unsigned long long b2 = __ballot(v2 == m2);
    int e2 = (__ffsll(b2) - 1) & 15;
    if (lane < 16)
        gates[(size_t)t * 16 + e] = (e == e1) ? m1 : (e == e2 ? m2 : 0.0f);
    if (lane == 0) {
        int p1 = atomicAdd(&cnt[e1], 1);
        list[e1 * 4096 + p1] = t;
        int p2 = atomicAdd(&cnt[e2], 1);
        list[e2 * 4096 + p2] = t;
    }
}

extern "C" void kernel_launch(void* const* d_in, const int* in_sizes, int n_in,
                              void* d_out, int out_size, void* d_ws, size_t ws_size,
                              hipStream_t stream) {
    const float* x    = (const float*)d_in[0];
    const float* Wq   = (const float*)d_in[1];
    const float* Wk   = (const float*)d_in[2];
    const float* Wv   = (const float*)d_in[3];
    const float* Wo   = (const float*)d_in[4];
    const float* ln1s = (const float*)d_in[5];
    const float* ln1b = (const float*)d_in[6];
    const float* ln2s = (const float*)d_in[7];
    const float* ln2b = (const float*)d_in[8];
    const float* Wsel = (const float*)d_in[9];
    const float* W1   = (const float*)d_in[10];
    const float* W2   = (const float*)d_in[11];
    float* out = (float*)d_out;

    // Workspace (96 MB, liveness-overlaid):
    //  [0,8)    h1_hi -> vT_hi -> h2
    //  [8,16)   h1_lo -> vT_lo -> gates(256KB) + cnt(@9MB) + list(@9MB+4KB, 256KB)
    //  [16,48)  q/k hi/lo -> up_buf (32MB compact sparse up)
    //  [48,64)  v hi/lo -> ctx hi/lo
    //  [64,80)  x2 fp32
    //  [80,96)  Wqkv/WoT splits -> W1T [80,88) + W2T [88,96)
    char* ws = (char*)d_ws;
    const size_t MB = 1024 * 1024;
    u16*   h1_h  = (u16*)  (ws + 0 * MB);
    u16*   h1_l  = (u16*)  (ws + 8 * MB);
    u16*   vT_hi = (u16*)  (ws + 0 * MB);
    u16*   vT_lo = (u16*)  (ws + 8 * MB);
    u16*   h2    = (u16*)  (ws + 0 * MB);
    float* gates = (float*)(ws + 8 * MB);
    int*   cnt   = (int*)  (ws + 9 * MB);
    int*   list  = (int*)  (ws + 9 * MB + 4096);
    u16*   q_hi  = (u16*)  (ws + 16 * MB);
    u16*   q_lo  = (u16*)  (ws + 24 * MB);
    u16*   k_hi  = (u16*)  (ws + 32 * MB);
    u16*   k_lo  = (u16*)  (ws + 40 * MB);
    u16*   up    = (u16*)  (ws + 16 * MB);
    u16*   v_hi  = (u16*)  (ws + 48 * MB);
    u16*   v_lo  = (u16*)  (ws + 56 * MB);
    u16*   ctx_h = (u16*)  (ws + 48 * MB);
    u16*   ctx_l = (u16*)  (ws + 56 * MB);
    float* x2    = (float*)(ws + 64 * MB);
    u16*   WqT_h = (u16*)  (ws + 80 * MB);
    u16*   WkT_h = (u16*)  (ws + 82 * MB);
    u16*   WvT_h = (u16*)  (ws + 84 * MB);
    u16*   WqT_l = (u16*)  (ws + 86 * MB);
    u16*   WkT_l = (u16*)  (ws + 88 * MB);
    u16*   WvT_l = (u16*)  (ws + 90 * MB);
    u16*   WoT_h = (u16*)  (ws + 92 * MB);
    u16*   WoT_l = (u16*)  (ws + 94 * MB);
    u16*   W1T   = (u16*)  (ws + 80 * MB);
    u16*   W2T   = (u16*)  (ws + 88 * MB);

    // weight transposes + one-time hi/lo splits
    transpose_split_kernel<<<dim3(32, 32), 256, 0, stream>>>(Wq, WqT_h, WqT_l, 1024, 1024);
    transpose_split_kernel<<<dim3(32, 32), 256, 0, stream>>>(Wk, WkT_h, WkT_l, 1024, 1024);
    transpose_split_kernel<<<dim3(32, 32), 256, 0, stream>>>(Wv, WvT_h, WvT_l, 1024, 1024);
    transpose_split_kernel<<<dim3(32, 32), 256, 0, stream>>>(Wo, WoT_h, WoT_l, 1024, 1024);

    // LN1 -> h1 hi/lo bf16
    ln_split_kernel<<<4096, 256, 0, stream>>>(x, ln1s, ln1b, h1_h, h1_l);
    // fused QKV projection (N=3072) -> bf16 hi/lo splits (Q pre-scaled 1/8)
    gemm3_qkv<<<dim3(24, 32), 256, 0, stream>>>(h1_h, h1_l, WqT_h, WqT_l, q_hi, q_lo, 0.125f);
    // V -> V^T per (b,h)
    vtrans_kernel<<<dim3(32, 32), 256, 0, stream>>>(v_hi, v_lo, vT_hi, vT_lo);
    // MFMA flash attention -> ctx hi/lo bf16
    attn_mfma<<<dim3(16, 32), 256, 0, stream>>>(q_hi, q_lo, k_hi, k_lo, vT_hi, vT_lo, ctx_h, ctx_l);
    // output projection + residual -> x2 fp32
    gemm3_res<<<dim3(8, 32), 256, 0, stream>>>(ctx_h, ctx_l, WoT_h, WoT_l, x2, x);
    // LN2 -> h2 bf16
    ln_f2b_kernel<<<4096, 256, 0, stream>>>(x2, ln2s, ln2b, h2);
    // router -> gates + per-expert token lists
    hipMemsetAsync(cnt, 0, 16 * sizeof(int), stream);
    router_kernel<<<1024, 256, 0, stream>>>(x2, ln2s, ln2b, Wsel, gates, cnt, list);
    // out = x2 (sparse down accumulates on top)
    init_out_kernel<<<4096, 256, 0, stream>>>(x2, out);
    // MoE weight pre-transposes to bf16 [N][K]
    transpose_f2b_kernel<<<dim3(8, 32, 16), 256, 0, stream>>>(W1, W1T, 1024, 256);
    transpose_f2b_kernel<<<dim3(32, 128, 1), 256, 0, stream>>>(W2, W2T, 4096, 1024);
    // sparse MoE: only routed (token,expert) pairs (top-2 of 16 => 8x less GEMM work)
    gemm_moe_up_sparse<<<dim3(2, 80), 256, 0, stream>>>(h2, W1T, cnt, list, gates, up);
    gemm_moe_down_sparse<<<dim3(8, 80), 256, 0, stream>>>(up, W2T, cnt, list, out);
}

// Round 12
// 666.583 us; speedup vs baseline: 1.0249x; 1.0249x over previous
//
#include <hip/hip_runtime.h>

typedef unsigned short u16;
typedef __attribute__((ext_vector_type(8))) short s16x8;
typedef __attribute__((ext_vector_type(4))) float f32x4;

typedef __attribute__((address_space(3))) unsigned int lds_u32_t;
typedef __attribute__((address_space(1))) unsigned int glb_u32_t;

__device__ __forceinline__ float bf2f(u16 u) {
    union { unsigned int i; float f; } c; c.i = ((unsigned int)u) << 16; return c.f;
}
__device__ __forceinline__ u16 f2bf(float f) {
    union { float f; unsigned int u; } c; c.f = f;
    unsigned int u = c.u;
    unsigned int r = (u + 0x7fffu + ((u >> 16) & 1u)) >> 16;
    return (u16)r;
}
// async global->LDS, 16B/lane; dest = wave-uniform base + lane*16; global SRC is per-lane.
__device__ __forceinline__ void glds16(const u16* g, short* l) {
    __builtin_amdgcn_global_load_lds((glb_u32_t*)g, (lds_u32_t*)l, 16, 0, 0);
}

// ------------- transpose fp32 [R][C] -> bf16 hi/lo [C][R]  (Wq/Wk/Wv/Wo, split once) ---
__global__ __launch_bounds__(256) void transpose_split_kernel(const float* __restrict__ src,
                                                              u16* __restrict__ dh,
                                                              u16* __restrict__ dl,
                                                              int R, int C) {
    __shared__ float tile[32][33];
    int c0 = blockIdx.x * 32, r0 = blockIdx.y * 32;
    int tx = threadIdx.x & 31, ty = threadIdx.x >> 5;
    for (int i = 0; i < 4; i++)
        tile[ty + 8 * i][tx] = src[(size_t)(r0 + ty + 8 * i) * C + c0 + tx];
    __syncthreads();
    for (int i = 0; i < 4; i++) {
        float v = tile[tx][ty + 8 * i];
        u16 hb = f2bf(v);
        size_t idx = (size_t)(c0 + ty + 8 * i) * R + r0 + tx;
        dh[idx] = hb;
        dl[idx] = f2bf(v - bf2f(hb));
    }
}

// ------------- transpose fp32 [R][C] -> bf16 [C][R], blockIdx.z slice (W1/W2 -> [N][K]) -
__global__ __launch_bounds__(256) void transpose_f2b_kernel(const float* __restrict__ src,
                                                            u16* __restrict__ dst,
                                                            int R, int C) {
    __shared__ float tile[32][33];
    size_t zoff = (size_t)blockIdx.z * R * C;
    int c0 = blockIdx.x * 32, r0 = blockIdx.y * 32;
    int tx = threadIdx.x & 31, ty = threadIdx.x >> 5;
    for (int i = 0; i < 4; i++)
        tile[ty + 8 * i][tx] = src[zoff + (size_t)(r0 + ty + 8 * i) * C + c0 + tx];
    __syncthreads();
    for (int i = 0; i < 4; i++)
        dst[zoff + (size_t)(c0 + ty + 8 * i) * R + r0 + tx] = f2bf(tile[tx][ty + 8 * i]);
}

// ------------- layernorm fp32 -> bf16 hi/lo split (h1, split once) -------------
__global__ __launch_bounds__(256) void ln_split_kernel(const float* __restrict__ x,
                                                       const float* __restrict__ sc,
                                                       const float* __restrict__ bi,
                                                       u16* __restrict__ oh,
                                                       u16* __restrict__ ol) {
    int row = blockIdx.x, tid = threadIdx.x;
    f32x4 u = *(const f32x4*)(x + (size_t)row * 1024 + tid * 4);
    float s = u[0] + u[1] + u[2] + u[3];
    float ss = u[0]*u[0] + u[1]*u[1] + u[2]*u[2] + u[3]*u[3];
    for (int off = 1; off < 64; off <<= 1) { s += __shfl_xor(s, off, 64); ss += __shfl_xor(ss, off, 64); }
    __shared__ float red[8];
    if ((tid & 63) == 0) { red[tid >> 6] = s; red[4 + (tid >> 6)] = ss; }
    __syncthreads();
    s = red[0] + red[1] + red[2] + red[3];
    ss = red[4] + red[5] + red[6] + red[7];
    float mu = s * (1.0f / 1024.0f);
    float rstd = rsqrtf(ss * (1.0f / 1024.0f) - mu * mu + 1e-5f);
    f32x4 g = *(const f32x4*)(sc + tid * 4);
    f32x4 b = *(const f32x4*)(bi + tid * 4);
    size_t o = (size_t)row * 1024 + tid * 4;
    for (int i = 0; i < 4; i++) {
        float v = (u[i] - mu) * rstd * g[i] + b[i];
        u16 hb = f2bf(v);
        oh[o + i] = hb;
        ol[o + i] = f2bf(v - bf2f(hb));
    }
}

// ------------- layernorm fp32 -> bf16 (MoE GEMM input) -------------
__global__ __launch_bounds__(256) void ln_f2b_kernel(const float* __restrict__ x,
                                                     const float* __restrict__ sc,
                                                     const float* __restrict__ bi,
                                                     u16* __restrict__ out) {
    int row = blockIdx.x, tid = threadIdx.x;
    f32x4 u = *(const f32x4*)(x + (size_t)row * 1024 + tid * 4);
    float s = u[0] + u[1] + u[2] + u[3];
    float ss = u[0]*u[0] + u[1]*u[1] + u[2]*u[2] + u[3]*u[3];
    for (int off = 1; off < 64; off <<= 1) { s += __shfl_xor(s, off, 64); ss += __shfl_xor(ss, off, 64); }
    __shared__ float red[8];
    if ((tid & 63) == 0) { red[tid >> 6] = s; red[4 + (tid >> 6)] = ss; }
    __syncthreads();
    s = red[0] + red[1] + red[2] + red[3];
    ss = red[4] + red[5] + red[6] + red[7];
    float mu = s * (1.0f / 1024.0f);
    float rstd = rsqrtf(ss * (1.0f / 1024.0f) - mu * mu + 1e-5f);
    f32x4 g = *(const f32x4*)(sc + tid * 4);
    f32x4 b = *(const f32x4*)(bi + tid * 4);
    u16* op = out + (size_t)row * 1024 + tid * 4;
    for (int i = 0; i < 4; i++)
        op[i] = f2bf((u[i] - mu) * rstd * g[i] + b[i]);
}

// ------------- fused QKV GEMM: glds staging + static epilogue --------------------------
__global__ __launch_bounds__(256) void gemm3_qkv(const u16* __restrict__ Ah_g,
                                                 const u16* __restrict__ Al_g,
                                                 const u16* __restrict__ Bh_g,
                                                 const u16* __restrict__ Bl_g,
                                                 u16* __restrict__ Ch, u16* __restrict__ Cl,
                                                 float scale) {
    const int K = 1024;
    __shared__ __align__(16) short Ahs[128 * 32], Als[128 * 32];
    __shared__ __align__(16) short Bhs[128 * 32], Bls[128 * 32];
    int m0 = blockIdx.y * 128, n0 = blockIdx.x * 128;
    int tid = threadIdx.x, lane = tid & 63, w = tid >> 6;
    int wm = (w & 1) * 64, wn = (w >> 1) * 64;
    int lr = lane & 15, lq = lane >> 4;
    int r0 = w * 32 + (lane >> 2);
    int cv = (lane & 3) * 8;
    const u16* pAh = Ah_g + (size_t)(m0 + r0) * K + cv;
    const u16* pAl = Al_g + (size_t)(m0 + r0) * K + cv;
    const u16* pBh = Bh_g + (size_t)(n0 + r0) * K + cv;
    const u16* pBl = Bl_g + (size_t)(n0 + r0) * K + cv;
    size_t st16 = (size_t)16 * K;
    f32x4 acc[4][4] = {};

    for (int k0 = 0; k0 < K; k0 += 32) {
        glds16(pAh + k0, &Ahs[w * 1024]);  glds16(pAh + k0 + st16, &Ahs[w * 1024 + 512]);
        glds16(pAl + k0, &Als[w * 1024]);  glds16(pAl + k0 + st16, &Als[w * 1024 + 512]);
        glds16(pBh + k0, &Bhs[w * 1024]);  glds16(pBh + k0 + st16, &Bhs[w * 1024 + 512]);
        glds16(pBl + k0, &Bls[w * 1024]);  glds16(pBl + k0 + st16, &Bls[w * 1024 + 512]);
        __syncthreads();   // barrier drains vmcnt: glds writes visible
        s16x8 ah[4], al[4], bh[4], bl[4];
        #pragma unroll
        for (int i = 0; i < 4; i++) {
            int off = (wm + i * 16 + lr) * 32 + lq * 8;
            ah[i] = *(const s16x8*)&Ahs[off];
            al[i] = *(const s16x8*)&Als[off];
        }
        #pragma unroll
        for (int j = 0; j < 4; j++) {
            int off = (wn + j * 16 + lr) * 32 + lq * 8;
            bh[j] = *(const s16x8*)&Bhs[off];
            bl[j] = *(const s16x8*)&Bls[off];
        }
        #pragma unroll
        for (int i = 0; i < 4; i++)
            #pragma unroll
            for (int j = 0; j < 4; j++) {
                acc[i][j] = __builtin_amdgcn_mfma_f32_16x16x32_bf16(al[i], bh[j], acc[i][j], 0, 0, 0);
                acc[i][j] = __builtin_amdgcn_mfma_f32_16x16x32_bf16(ah[i], bl[j], acc[i][j], 0, 0, 0);
                acc[i][j] = __builtin_amdgcn_mfma_f32_16x16x32_bf16(ah[i], bh[j], acc[i][j], 0, 0, 0);
            }
        __syncthreads();
    }

    int seg = n0 >> 10;
    float sc = (seg == 0) ? scale : 1.0f;
    u16* Chp = Ch + (size_t)seg * 8388608;
    u16* Clp = Cl + (size_t)seg * 8388608;
    int c0 = (n0 & 1023) + wn;
    #pragma unroll
    for (int i = 0; i < 4; i++)
        #pragma unroll
        for (int j = 0; j < 4; j++)
            #pragma unroll
            for (int r = 0; r < 4; r++) {
                int row = m0 + wm + i * 16 + lq * 4 + r;
                int col = c0 + j * 16 + lr;
                float vv = acc[i][j][r] * sc;
                u16 hb = f2bf(vv);
                u16 lb = f2bf(vv - bf2f(hb));
                size_t idx = (size_t)row * 1024 + col;
                Chp[idx] = hb; Clp[idx] = lb;
            }
}

// ------------- Wo GEMM: glds staging, fp32 C = A@B^T + res ----------------------------
__global__ __launch_bounds__(256) void gemm3_res(const u16* __restrict__ Ah_g,
                                                 const u16* __restrict__ Al_g,
                                                 const u16* __restrict__ Bh_g,
                                                 const u16* __restrict__ Bl_g,
                                                 float* __restrict__ C,
                                                 const float* __restrict__ res) {
    const int K = 1024, N = 1024;
    __shared__ __align__(16) short Ahs[128 * 32], Als[128 * 32];
    __shared__ __align__(16) short Bhs[128 * 32], Bls[128 * 32];
    int m0 = blockIdx.y * 128, n0 = blockIdx.x * 128;
    int tid = threadIdx.x, lane = tid & 63, w = tid >> 6;
    int wm = (w & 1) * 64, wn = (w >> 1) * 64;
    int lr = lane & 15, lq = lane >> 4;
    int r0 = w * 32 + (lane >> 2);
    int cv = (lane & 3) * 8;
    const u16* pAh = Ah_g + (size_t)(m0 + r0) * K + cv;
    const u16* pAl = Al_g + (size_t)(m0 + r0) * K + cv;
    const u16* pBh = Bh_g + (size_t)(n0 + r0) * K + cv;
    const u16* pBl = Bl_g + (size_t)(n0 + r0) * K + cv;
    size_t st16 = (size_t)16 * K;
    f32x4 acc[4][4] = {};

    for (int k0 = 0; k0 < K; k0 += 32) {
        glds16(pAh + k0, &Ahs[w * 1024]);  glds16(pAh + k0 + st16, &Ahs[w * 1024 + 512]);
        glds16(pAl + k0, &Als[w * 1024]);  glds16(pAl + k0 + st16, &Als[w * 1024 + 512]);
        glds16(pBh + k0, &Bhs[w * 1024]);  glds16(pBh + k0 + st16, &Bhs[w * 1024 + 512]);
        glds16(pBl + k0, &Bls[w * 1024]);  glds16(pBl + k0 + st16, &Bls[w * 1024 + 512]);
        __syncthreads();
        s16x8 ah[4], al[4], bh[4], bl[4];
        #pragma unroll
        for (int i = 0; i < 4; i++) {
            int off = (wm + i * 16 + lr) * 32 + lq * 8;
            ah[i] = *(const s16x8*)&Ahs[off];
            al[i] = *(const s16x8*)&Als[off];
        }
        #pragma unroll
        for (int j = 0; j < 4; j++) {
            int off = (wn + j * 16 + lr) * 32 + lq * 8;
            bh[j] = *(const s16x8*)&Bhs[off];
            bl[j] = *(const s16x8*)&Bls[off];
        }
        #pragma unroll
        for (int i = 0; i < 4; i++)
            #pragma unroll
            for (int j = 0; j < 4; j++) {
                acc[i][j] = __builtin_amdgcn_mfma_f32_16x16x32_bf16(al[i], bh[j], acc[i][j], 0, 0, 0);
                acc[i][j] = __builtin_amdgcn_mfma_f32_16x16x32_bf16(ah[i], bl[j], acc[i][j], 0, 0, 0);
                acc[i][j] = __builtin_amdgcn_mfma_f32_16x16x32_bf16(ah[i], bh[j], acc[i][j], 0, 0, 0);
            }
        __syncthreads();
    }

    #pragma unroll
    for (int i = 0; i < 4; i++)
        #pragma unroll
        for (int j = 0; j < 4; j++)
            #pragma unroll
            for (int r = 0; r < 4; r++) {
                int row = m0 + wm + i * 16 + lq * 4 + r;
                int col = n0 + wn + j * 16 + lr;
                size_t idx = (size_t)row * N + col;
                C[idx] = acc[i][j][r] + res[idx];
            }
}

// ------------- sparse MoE up: per-expert gathered GEMM, compact slots -----------------
// grid (2, 80). Tile-walk over cnt[] also accumulates base_e (prefix sum) -- compact
// slot = base_e + p. Per-row math BIT-IDENTICAL to dense (same K-order, B rows,
// relu*gate*f2bf). No atomics anywhere.
__global__ __launch_bounds__(256) void gemm_moe_up_sparse(const u16* __restrict__ h2,
                                                          const u16* __restrict__ W1T,
                                                          const int* __restrict__ cnt,
                                                          const int* __restrict__ list,
                                                          const float* __restrict__ gates,
                                                          u16* __restrict__ up_buf) {
    const int K = 1024;
    __shared__ __align__(16) short As[128 * 32];
    __shared__ __align__(16) short Bs[128 * 32];
    int e = -1, tstart = 0, base_e = 0;
    {
        int ty = blockIdx.y, at = 0, bs = 0;
        for (int i = 0; i < 16; i++) {
            int c = cnt[i];
            int nt = (c + 127) >> 7;
            if (e < 0 && ty < at + nt) { e = i; tstart = (ty - at) * 128; base_e = bs; }
            at += nt; bs += c;
        }
    }
    if (e < 0) return;
    int ncnt = cnt[e];
    int n0 = blockIdx.x * 128;
    int tid = threadIdx.x, lane = tid & 63, w = tid >> 6;
    int wm = (w & 1) * 64, wn = (w >> 1) * 64;
    int lr = lane & 15, lq = lane >> 4;
    int r0 = w * 32 + (lane >> 2);
    int cv = (lane & 3) * 8;
    int p0 = tstart + r0, p1 = tstart + r0 + 16;
    int t0 = list[e * 4096 + (p0 < ncnt ? p0 : ncnt - 1)];
    int t1 = list[e * 4096 + (p1 < ncnt ? p1 : ncnt - 1)];
    const u16* pA0 = h2 + (size_t)t0 * K + cv;
    const u16* pA1 = h2 + (size_t)t1 * K + cv;
    const u16* pB  = W1T + (size_t)(e * 256 + n0 + r0) * K + cv;
    size_t st16 = (size_t)16 * K;
    f32x4 acc[4][4] = {};

    for (int k0 = 0; k0 < K; k0 += 32) {
        glds16(pA0 + k0, &As[w * 1024]);  glds16(pA1 + k0, &As[w * 1024 + 512]);
        glds16(pB + k0, &Bs[w * 1024]);   glds16(pB + k0 + st16, &Bs[w * 1024 + 512]);
        __syncthreads();
        s16x8 av[4], bv[4];
        #pragma unroll
        for (int i = 0; i < 4; i++) av[i] = *(const s16x8*)&As[(wm + i * 16 + lr) * 32 + lq * 8];
        #pragma unroll
        for (int j = 0; j < 4; j++) bv[j] = *(const s16x8*)&Bs[(wn + j * 16 + lr) * 32 + lq * 8];
        #pragma unroll
        for (int i = 0; i < 4; i++)
            #pragma unroll
            for (int j = 0; j < 4; j++)
                acc[i][j] = __builtin_amdgcn_mfma_f32_16x16x32_bf16(av[i], bv[j], acc[i][j], 0, 0, 0);
        __syncthreads();
    }

    #pragma unroll
    for (int i = 0; i < 4; i++)
        #pragma unroll
        for (int j = 0; j < 4; j++)
            #pragma unroll
            for (int r = 0; r < 4; r++) {
                int rl = wm + i * 16 + lq * 4 + r;
                int p = tstart + rl;
                if (p < ncnt) {
                    int t = list[e * 4096 + p];
                    float g = gates[(size_t)t * 16 + e];
                    int col = n0 + wn + j * 16 + lr;
                    up_buf[(size_t)(base_e + p) * 256 + col] = f2bf(fmaxf(acc[i][j][r], 0.0f) * g);
                }
            }
}

// ------------- sparse MoE down: per-expert GEMM (K=256), PLAIN STORES -----------------
// grid (8, 80). Writes fp32 contribution per (pair, col) to compact down_buf --
// round-11's 8.4M atomicAdds (the +45us regression) replaced by plain stores;
// the 2-way reduction moves to gather_out (deterministic e1-then-e2 order).
__global__ __launch_bounds__(256) void gemm_moe_down_sparse(const u16* __restrict__ up_buf,
                                                            const u16* __restrict__ W2T,
                                                            const int* __restrict__ cnt,
                                                            float* __restrict__ down_buf) {
    const int K = 256;
    __shared__ __align__(16) short As[128 * 32];
    __shared__ __align__(16) short Bs[128 * 32];
    int e = -1, tstart = 0, base_e = 0;
    {
        int ty = blockIdx.y, at = 0, bs = 0;
        for (int i = 0; i < 16; i++) {
            int c = cnt[i];
            int nt = (c + 127) >> 7;
            if (e < 0 && ty < at + nt) { e = i; tstart = (ty - at) * 128; base_e = bs; }
            at += nt; bs += c;
        }
    }
    if (e < 0) return;
    int ncnt = cnt[e];
    int n0 = blockIdx.x * 128;
    int tid = threadIdx.x, lane = tid & 63, w = tid >> 6;
    int wm = (w & 1) * 64, wn = (w >> 1) * 64;
    int lr = lane & 15, lq = lane >> 4;
    int r0 = w * 32 + (lane >> 2);
    int cv = (lane & 3) * 8;
    int p0 = tstart + r0, p1 = tstart + r0 + 16;
    int pc0 = p0 < ncnt ? p0 : ncnt - 1;
    int pc1 = p1 < ncnt ? p1 : ncnt - 1;
    const u16* pA0 = up_buf + (size_t)(base_e + pc0) * 256 + cv;
    const u16* pA1 = up_buf + (size_t)(base_e + pc1) * 256 + cv;
    const u16* pB  = W2T + (size_t)(n0 + r0) * 4096 + e * 256 + cv;
    size_t st16 = (size_t)16 * 4096;
    f32x4 acc[4][4] = {};

    for (int k0 = 0; k0 < K; k0 += 32) {
        glds16(pA0 + k0, &As[w * 1024]);  glds16(pA1 + k0, &As[w * 1024 + 512]);
        glds16(pB + k0, &Bs[w * 1024]);   glds16(pB + k0 + st16, &Bs[w * 1024 + 512]);
        __syncthreads();
        s16x8 av[4], bv[4];
        #pragma unroll
        for (int i = 0; i < 4; i++) av[i] = *(const s16x8*)&As[(wm + i * 16 + lr) * 32 + lq * 8];
        #pragma unroll
        for (int j = 0; j < 4; j++) bv[j] = *(const s16x8*)&Bs[(wn + j * 16 + lr) * 32 + lq * 8];
        #pragma unroll
        for (int i = 0; i < 4; i++)
            #pragma unroll
            for (int j = 0; j < 4; j++)
                acc[i][j] = __builtin_amdgcn_mfma_f32_16x16x32_bf16(av[i], bv[j], acc[i][j], 0, 0, 0);
        __syncthreads();
    }

    #pragma unroll
    for (int i = 0; i < 4; i++)
        #pragma unroll
        for (int j = 0; j < 4; j++)
            #pragma unroll
            for (int r = 0; r < 4; r++) {
                int rl = wm + i * 16 + lq * 4 + r;
                int p = tstart + rl;
                if (p < ncnt) {
                    int col = n0 + wn + j * 16 + lr;
                    down_buf[(size_t)(base_e + p) * 1024 + col] = acc[i][j][r];
                }
            }
}

// ------------- gather: out[t] = x2[t] + c_e1[t] + c_e2[t] (deterministic order) -------
__global__ __launch_bounds__(256) void gather_out_kernel(const float* __restrict__ x2,
                                                         const float* __restrict__ down_buf,
                                                         const int* __restrict__ cnt,
                                                         const int* __restrict__ pidx,
                                                         float* __restrict__ out) {
    int t = blockIdx.x, tid = threadIdx.x;
    int i1 = pidx[t * 2], i2 = pidx[t * 2 + 1];
    int e1 = i1 >> 12, p1 = i1 & 4095;
    int e2 = i2 >> 12, p2 = i2 & 4095;
    int b1 = 0, b2 = 0;
    for (int i = 0; i < 16; i++) {
        int c = cnt[i];
        if (i < e1) b1 += c;
        if (i < e2) b2 += c;
    }
    size_t o = (size_t)t * 1024 + tid * 4;
    f32x4 a  = *(const f32x4*)(x2 + o);
    f32x4 c1 = *(const f32x4*)(down_buf + (size_t)(b1 + p1) * 1024 + tid * 4);
    f32x4 c2 = *(const f32x4*)(down_buf + (size_t)(b2 + p2) * 1024 + tid * 4);
    for (int k = 0; k < 4; k++) a[k] = a[k] + c1[k] + c2[k];
    *(f32x4*)(out + o) = a;
}

// ------------- V transpose: v_hi/lo [4096][1024] -> vT_hi/lo [32 bh][64 d][2048 s] -------
__global__ __launch_bounds__(256) void vtrans_kernel(const u16* __restrict__ v_hi,
                                                     const u16* __restrict__ v_lo,
                                                     u16* __restrict__ vT_hi,
                                                     u16* __restrict__ vT_lo) {
    __shared__ __align__(16) short tile[64][72];
    int st = blockIdx.x, bh = blockIdx.y;
    int b = bh >> 4, h = bh & 15;
    int tid = threadIdx.x;
    int i = tid >> 2, seg = (tid & 3) * 16;
    for (int p = 0; p < 2; p++) {
        const u16* src = p ? v_lo : v_hi;
        u16* dst = p ? vT_lo : vT_hi;
        size_t goff = (size_t)(b * 2048 + st * 64 + i) * 1024 + h * 64 + seg;
        *(s16x8*)&tile[i][seg]     = *(const s16x8*)&src[goff];
        *(s16x8*)&tile[i][seg + 8] = *(const s16x8*)&src[goff + 8];
        __syncthreads();
        s16x8 o0, o1;
        for (int j = 0; j < 8; j++) { o0[j] = tile[seg + j][i]; o1[j] = tile[seg + 8 + j][i]; }
        size_t doff = ((size_t)bh * 64 + i) * 2048 + st * 64 + seg;
        *(s16x8*)&dst[doff]     = o0;
        *(s16x8*)&dst[doff + 8] = o1;
        __syncthreads();
    }
}

// ------------- MFMA flash attention, split-bf16 (3-term), online softmax -------------
// EXACT round-9 kernel (204.5us re-measured round 11): 128-row blocks, XCD swizzle,
// swizzled P buffer [16*64] (idx ^= (row&7)<<3 both sides), Ph+Pl 3-term PV.
__global__ __launch_bounds__(256) void attn_mfma(const u16* __restrict__ qh_g,
                                                 const u16* __restrict__ ql_g,
                                                 const u16* __restrict__ kh_g,
                                                 const u16* __restrict__ kl_g,
                                                 const u16* __restrict__ vth_g,
                                                 const u16* __restrict__ vtl_g,
                                                 u16* __restrict__ ch_g,
                                                 u16* __restrict__ cl_g) {
    __shared__ __align__(16) short Ksh[64][72], Ksl[64][72], Vsh[64][72], Vsl[64][72];
    __shared__ __align__(16) short Ph[4][16 * 64], Pl[4][16 * 64];
    int lin = blockIdx.x + 16 * blockIdx.y;
    int xcd = lin & 7, rest = lin >> 3;
    int qt = rest & 15;
    int bh = xcd + 8 * (rest >> 4);
    int b = bh >> 4, h = bh & 15;
    int tid = threadIdx.x, w = tid >> 6, lane = tid & 63;
    int lr = lane & 15, lq = lane >> 4;
    int qbase = qt * 128 + w * 32;

    s16x8 qfh[2][2], qfl[2][2];
    for (int rt = 0; rt < 2; rt++)
        for (int kc = 0; kc < 2; kc++) {
            size_t qoff = (size_t)(b * 2048 + qbase + rt * 16 + lr) * 1024 + h * 64 + kc * 32 + lq * 8;
            qfh[rt][kc] = *(const s16x8*)&qh_g[qoff];
            qfl[rt][kc] = *(const s16x8*)&ql_g[qoff];
        }

    float m_[2][4], l_[2][4];
    f32x4 O[2][4] = {};
    for (int rt = 0; rt < 2; rt++)
        for (int r = 0; r < 4; r++) { m_[rt][r] = -1e30f; l_[rt][r] = 0.0f; }

    for (int kc0 = 0; kc0 < 2048; kc0 += 64) {
        {   // stage K chunk [key][d] and V^T chunk [d][key] (L2-hits after swizzle)
            int kk = tid >> 2, seg = (tid & 3) * 16;
            size_t goff = (size_t)(b * 2048 + kc0 + kk) * 1024 + h * 64 + seg;
            *(s16x8*)&Ksh[kk][seg]     = *(const s16x8*)&kh_g[goff];
            *(s16x8*)&Ksh[kk][seg + 8] = *(const s16x8*)&kh_g[goff + 8];
            *(s16x8*)&Ksl[kk][seg]     = *(const s16x8*)&kl_g[goff];
            *(s16x8*)&Ksl[kk][seg + 8] = *(const s16x8*)&kl_g[goff + 8];
            size_t voff = ((size_t)bh * 64 + kk) * 2048 + kc0 + seg;
            *(s16x8*)&Vsh[kk][seg]     = *(const s16x8*)&vth_g[voff];
            *(s16x8*)&Vsh[kk][seg + 8] = *(const s16x8*)&vth_g[voff + 8];
            *(s16x8*)&Vsl[kk][seg]     = *(const s16x8*)&vtl_g[voff];
            *(s16x8*)&Vsl[kk][seg + 8] = *(const s16x8*)&vtl_g[voff + 8];
        }
        __syncthreads();

        f32x4 s[2][4] = {};
        for (int ct = 0; ct < 4; ct++)
            for (int kc = 0; kc < 2; kc++) {
                s16x8 kbh = *(const s16x8*)&Ksh[ct * 16 + lr][kc * 32 + lq * 8];
                s16x8 kbl = *(const s16x8*)&Ksl[ct * 16 + lr][kc * 32 + lq * 8];
                for (int rt = 0; rt < 2; rt++) {
                    s[rt][ct] = __builtin_amdgcn_mfma_f32_16x16x32_bf16(qfl[rt][kc], kbh, s[rt][ct], 0, 0, 0);
                    s[rt][ct] = __builtin_amdgcn_mfma_f32_16x16x32_bf16(qfh[rt][kc], kbl, s[rt][ct], 0, 0, 0);
                    s[rt][ct] = __builtin_amdgcn_mfma_f32_16x16x32_bf16(qfh[rt][kc], kbh, s[rt][ct], 0, 0, 0);
                }
            }

        for (int rt = 0; rt < 2; rt++) {
            float al[4];
            for (int ri = 0; ri < 4; ri++) {
                float mx = fmaxf(fmaxf(s[rt][0][ri], s[rt][1][ri]), fmaxf(s[rt][2][ri], s[rt][3][ri]));
                for (int off = 1; off < 16; off <<= 1) mx = fmaxf(mx, __shfl_xor(mx, off, 64));
                float mn = fmaxf(m_[rt][ri], mx);
                float a = __expf(m_[rt][ri] - mn);
                m_[rt][ri] = mn; al[ri] = a;
                float ps = 0.0f;
                for (int ct = 0; ct < 4; ct++) {
                    float p = __expf(s[rt][ct][ri] - mn);
                    s[rt][ct][ri] = p; ps += p;
                }
                for (int off = 1; off < 16; off <<= 1) ps += __shfl_xor(ps, off, 64);
                l_[rt][ri] = l_[rt][ri] * a + ps;
            }
            for (int nt = 0; nt < 4; nt++)
                for (int ri = 0; ri < 4; ri++) O[rt][nt][ri] *= al[ri];
            for (int ct = 0; ct < 4; ct++)
                for (int ri = 0; ri < 4; ri++) {
                    float p = s[rt][ct][ri];
                    u16 hb = f2bf(p);
                    u16 lb = f2bf(p - bf2f(hb));
                    int row = lq * 4 + ri, col = ct * 16 + lr;
                    int pidx = (row * 64 + col) ^ ((row & 7) << 3);
                    Ph[w][pidx] = (short)hb;
                    Pl[w][pidx] = (short)lb;
                }
            asm volatile("s_waitcnt lgkmcnt(0)" ::: "memory");
            __builtin_amdgcn_sched_barrier(0);
            __builtin_amdgcn_s_setprio(1);
            for (int kc = 0; kc < 2; kc++) {
                int pidx = (lr * 64 + kc * 32 + lq * 8) ^ ((lr & 7) << 3);
                s16x8 pah = *(const s16x8*)&Ph[w][pidx];
                s16x8 pal = *(const s16x8*)&Pl[w][pidx];
                for (int nt = 0; nt < 4; nt++) {
                    s16x8 vbh = *(const s16x8*)&Vsh[nt * 16 + lr][kc * 32 + lq * 8];
                    s16x8 vbl = *(const s16x8*)&Vsl[nt * 16 + lr][kc * 32 + lq * 8];
                    O[rt][nt] = __builtin_amdgcn_mfma_f32_16x16x32_bf16(pal, vbh, O[rt][nt], 0, 0, 0);
                    O[rt][nt] = __builtin_amdgcn_mfma_f32_16x16x32_bf16(pah, vbl, O[rt][nt], 0, 0, 0);
                    O[rt][nt] = __builtin_amdgcn_mfma_f32_16x16x32_bf16(pah, vbh, O[rt][nt], 0, 0, 0);
                }
            }
            __builtin_amdgcn_s_setprio(0);
            asm volatile("s_waitcnt lgkmcnt(0)" ::: "memory");
            __builtin_amdgcn_sched_barrier(0);
        }
        __syncthreads();
    }

    for (int rt = 0; rt < 2; rt++)
        for (int nt = 0; nt < 4; nt++)
            for (int ri = 0; ri < 4; ri++) {
                int row = qbase + rt * 16 + lq * 4 + ri;
                int d = nt * 16 + lr;
                float v = O[rt][nt][ri] / l_[rt][ri];
                u16 hb = f2bf(v);
                size_t idx = (size_t)(b * 2048 + row) * 1024 + h * 64 + d;
                ch_g[idx] = hb;
                cl_g[idx] = f2bf(v - bf2f(hb));
            }
}

// ------------- router: pure fp32 + expert token-list + per-token slot record ----------
__global__ __launch_bounds__(256) void router_kernel(const float* __restrict__ x2,
                                                     const float* __restrict__ sc,
                                                     const float* __restrict__ bi,
                                                     const float* __restrict__ Wsel,
                                                     float* __restrict__ gates,
                                                     int* __restrict__ cnt,
                                                     int* __restrict__ list,
                                                     int* __restrict__ pidx) {
    int tid = threadIdx.x, w = tid >> 6, lane = tid & 63;
    int t = blockIdx.x * 4 + w;
    const float* xp = x2 + (size_t)t * 1024;
    float s = 0.0f, ss = 0.0f;
    for (int i = 0; i < 16; i++) {
        float v = xp[lane * 16 + i];
        s += v; ss += v * v;
    }
    for (int off = 1; off < 64; off <<= 1) { s += __shfl_xor(s, off, 64); ss += __shfl_xor(ss, off, 64); }
    float mu = s * (1.0f / 1024.0f);
    float rstd = rsqrtf(ss * (1.0f / 1024.0f) - mu * mu + 1e-5f);
    int e = lane & 15, part = lane >> 4;
    float acc = 0.0f;
    for (int d = part * 256; d < part * 256 + 256; d++) {
        float h = (xp[d] - mu) * rstd * sc[d] + bi[d];
        acc += h * Wsel[(size_t)d * 16 + e];
    }
    acc += __shfl_xor(acc, 16, 64);
    acc += __shfl_xor(acc, 32, 64);
    float v = 1.0f / (1.0f + __expf(-acc));
    float m1 = v;
    for (int off = 1; off < 64; off <<= 1) m1 = fmaxf(m1, __shfl_xor(m1, off, 64));
    unsigned long long b1 = __ballot(v == m1);
    int e1 = (__ffsll(b1) - 1) & 15;
    float v2 = (e == e1) ? -1e30f : v;
    float m2 = v2;
    for (int off = 1; off < 64; off <<= 1) m2 = fmaxf(m2, __shfl_xor(m2, off, 64));
    unsigned long long b2 = __ballot(v2 == m2);
    int e2 = (__ffsll(b2) - 1) & 15;
    if (lane < 16)
        gates[(size_t)t * 16 + e] = (e == e1) ? m1 : (e == e2 ? m2 : 0.0f);
    if (lane == 0) {
        int p1 = atomicAdd(&cnt[e1], 1);
        list[e1 * 4096 + p1] = t;
        pidx[t * 2] = (e1 << 12) | p1;
        int p2 = atomicAdd(&cnt[e2], 1);
        list[e2 * 4096 + p2] = t;
        pidx[t * 2 + 1] = (e2 << 12) | p2;
    }
}

extern "C" void kernel_launch(void* const* d_in, const int* in_sizes, int n_in,
                              void* d_out, int out_size, void* d_ws, size_t ws_size,
                              hipStream_t stream) {
    const float* x    = (const float*)d_in[0];
    const float* Wq   = (const float*)d_in[1];
    const float* Wk   = (const float*)d_in[2];
    const float* Wv   = (const float*)d_in[3];
    const float* Wo   = (const float*)d_in[4];
    const float* ln1s = (const float*)d_in[5];
    const float* ln1b = (const float*)d_in[6];
    const float* ln2s = (const float*)d_in[7];
    const float* ln2b = (const float*)d_in[8];
    const float* Wsel = (const float*)d_in[9];
    const float* W1   = (const float*)d_in[10];
    const float* W2   = (const float*)d_in[11];
    float* out = (float*)d_out;

    // Workspace (96 MB, liveness-overlaid):
    //  [0,8)    h1_hi -> vT_hi -> h2
    //  [8,16)   h1_lo -> vT_lo -> gates(256KB)@8MB + cnt@9MB + list@9MB+4KB + pidx@9.5MB
    //  [16,20)  q_hi -> up_buf (4MB compact bf16)
    //  [20,54)  q_lo/k_hi/k_lo partial -> down_buf (33.5MB compact fp32; [48,54) uses
    //           dead v/ctx space -- ctx dead after gemm3_res)
    //  [48,64)  v hi/lo -> ctx hi/lo (dead before down_buf written)
    //  [64,80)  x2 fp32
    //  [80,96)  Wqkv/WoT splits -> W1T [80,88) + W2T [88,96)
    char* ws = (char*)d_ws;
    const size_t MB = 1024 * 1024;
    u16*   h1_h  = (u16*)  (ws + 0 * MB);
    u16*   h1_l  = (u16*)  (ws + 8 * MB);
    u16*   vT_hi = (u16*)  (ws + 0 * MB);
    u16*   vT_lo = (u16*)  (ws + 8 * MB);
    u16*   h2    = (u16*)  (ws + 0 * MB);
    float* gates = (float*)(ws + 8 * MB);
    int*   cnt   = (int*)  (ws + 9 * MB);
    int*   list  = (int*)  (ws + 9 * MB + 4096);
    int*   pidx  = (int*)  (ws + 9 * MB + 512 * 1024);
    u16*   q_hi  = (u16*)  (ws + 16 * MB);
    u16*   q_lo  = (u16*)  (ws + 24 * MB);
    u16*   k_hi  = (u16*)  (ws + 32 * MB);
    u16*   k_lo  = (u16*)  (ws + 40 * MB);
    u16*   up    = (u16*)  (ws + 16 * MB);               // 8192*256*2 = 4MB
    float* dbuf  = (float*)(ws + 20 * MB);               // 8192*1024*4 = 33.5MB
    u16*   v_hi  = (u16*)  (ws + 48 * MB);
    u16*   v_lo  = (u16*)  (ws + 56 * MB);
    u16*   ctx_h = (u16*)  (ws + 48 * MB);
    u16*   ctx_l = (u16*)  (ws + 56 * MB);
    float* x2    = (float*)(ws + 64 * MB);
    u16*   WqT_h = (u16*)  (ws + 80 * MB);
    u16*   WkT_h = (u16*)  (ws + 82 * MB);
    u16*   WvT_h = (u16*)  (ws + 84 * MB);
    u16*   WqT_l = (u16*)  (ws + 86 * MB);
    u16*   WkT_l = (u16*)  (ws + 88 * MB);
    u16*   WvT_l = (u16*)  (ws + 90 * MB);
    u16*   WoT_h = (u16*)  (ws + 92 * MB);
    u16*   WoT_l = (u16*)  (ws + 94 * MB);
    u16*   W1T   = (u16*)  (ws + 80 * MB);
    u16*   W2T   = (u16*)  (ws + 88 * MB);

    // weight transposes + one-time hi/lo splits
    transpose_split_kernel<<<dim3(32, 32), 256, 0, stream>>>(Wq, WqT_h, WqT_l, 1024, 1024);
    transpose_split_kernel<<<dim3(32, 32), 256, 0, stream>>>(Wk, WkT_h, WkT_l, 1024, 1024);
    transpose_split_kernel<<<dim3(32, 32), 256, 0, stream>>>(Wv, WvT_h, WvT_l, 1024, 1024);
    transpose_split_kernel<<<dim3(32, 32), 256, 0, stream>>>(Wo, WoT_h, WoT_l, 1024, 1024);

    // LN1 -> h1 hi/lo bf16
    ln_split_kernel<<<4096, 256, 0, stream>>>(x, ln1s, ln1b, h1_h, h1_l);
    // fused QKV projection (N=3072) -> bf16 hi/lo splits (Q pre-scaled 1/8)
    gemm3_qkv<<<dim3(24, 32), 256, 0, stream>>>(h1_h, h1_l, WqT_h, WqT_l, q_hi, q_lo, 0.125f);
    // V -> V^T per (b,h)
    vtrans_kernel<<<dim3(32, 32), 256, 0, stream>>>(v_hi, v_lo, vT_hi, vT_lo);
    // MFMA flash attention -> ctx hi/lo bf16
    attn_mfma<<<dim3(16, 32), 256, 0, stream>>>(q_hi, q_lo, k_hi, k_lo, vT_hi, vT_lo, ctx_h, ctx_l);
    // output projection + residual -> x2 fp32
    gemm3_res<<<dim3(8, 32), 256, 0, stream>>>(ctx_h, ctx_l, WoT_h, WoT_l, x2, x);
    // LN2 -> h2 bf16
    ln_f2b_kernel<<<4096, 256, 0, stream>>>(x2, ln2s, ln2b, h2);
    // router -> gates + token lists + per-token slots
    hipMemsetAsync(cnt, 0, 16 * sizeof(int), stream);
    router_kernel<<<1024, 256, 0, stream>>>(x2, ln2s, ln2b, Wsel, gates, cnt, list, pidx);
    // MoE weight pre-transposes to bf16 [N][K]
    transpose_f2b_kernel<<<dim3(8, 32, 16), 256, 0, stream>>>(W1, W1T, 1024, 256);
    transpose_f2b_kernel<<<dim3(32, 128, 1), 256, 0, stream>>>(W2, W2T, 4096, 1024);
    // sparse MoE (8x less GEMM work), no atomics: up -> down (plain stores) -> gather
    gemm_moe_up_sparse<<<dim3(2, 80), 256, 0, stream>>>(h2, W1T, cnt, list, gates, up);
    gemm_moe_down_sparse<<<dim3(8, 80), 256, 0, stream>>>(up, W2T, cnt, dbuf);
    gather_out_kernel<<<4096, 256, 0, stream>>>(x2, dbuf, cnt, pidx, out);
}

// Round 13
// 633.928 us; speedup vs baseline: 1.0777x; 1.0515x over previous
//
#include <hip/hip_runtime.h>

typedef unsigned short u16;
typedef __attribute__((ext_vector_type(8))) short s16x8;
typedef __attribute__((ext_vector_type(4))) float f32x4;

typedef __attribute__((address_space(3))) unsigned int lds_u32_t;
typedef __attribute__((address_space(1))) unsigned int glb_u32_t;

__device__ __forceinline__ float bf2f(u16 u) {
    union { unsigned int i; float f; } c; c.i = ((unsigned int)u) << 16; return c.f;
}
__device__ __forceinline__ u16 f2bf(float f) {
    union { float f; unsigned int u; } c; c.f = f;
    unsigned int u = c.u;
    unsigned int r = (u + 0x7fffu + ((u >> 16) & 1u)) >> 16;
    return (u16)r;
}
// async global->LDS, 16B/lane; dest = wave-uniform base + lane*16.
__device__ __forceinline__ void glds16(const u16* g, short* l) {
    __builtin_amdgcn_global_load_lds((glb_u32_t*)g, (lds_u32_t*)l, 16, 0, 0);
}

// ------------- transpose fp32 [R][C] -> bf16 hi/lo [C][R]  (Wq/Wk/Wv/Wo, split once) ---
__global__ __launch_bounds__(256) void transpose_split_kernel(const float* __restrict__ src,
                                                              u16* __restrict__ dh,
                                                              u16* __restrict__ dl,
                                                              int R, int C) {
    __shared__ float tile[32][33];
    int c0 = blockIdx.x * 32, r0 = blockIdx.y * 32;
    int tx = threadIdx.x & 31, ty = threadIdx.x >> 5;
    for (int i = 0; i < 4; i++)
        tile[ty + 8 * i][tx] = src[(size_t)(r0 + ty + 8 * i) * C + c0 + tx];
    __syncthreads();
    for (int i = 0; i < 4; i++) {
        float v = tile[tx][ty + 8 * i];
        u16 hb = f2bf(v);
        size_t idx = (size_t)(c0 + ty + 8 * i) * R + r0 + tx;
        dh[idx] = hb;
        dl[idx] = f2bf(v - bf2f(hb));
    }
}

// ------------- transpose fp32 [R][C] -> bf16 [C][R], blockIdx.z slice (W1/W2 -> [N][K]) -
__global__ __launch_bounds__(256) void transpose_f2b_kernel(const float* __restrict__ src,
                                                            u16* __restrict__ dst,
                                                            int R, int C) {
    __shared__ float tile[32][33];
    size_t zoff = (size_t)blockIdx.z * R * C;
    int c0 = blockIdx.x * 32, r0 = blockIdx.y * 32;
    int tx = threadIdx.x & 31, ty = threadIdx.x >> 5;
    for (int i = 0; i < 4; i++)
        tile[ty + 8 * i][tx] = src[zoff + (size_t)(r0 + ty + 8 * i) * C + c0 + tx];
    __syncthreads();
    for (int i = 0; i < 4; i++)
        dst[zoff + (size_t)(c0 + ty + 8 * i) * R + r0 + tx] = f2bf(tile[tx][ty + 8 * i]);
}

// ------------- layernorm fp32 -> bf16 hi/lo split (h1, split once) -------------
__global__ __launch_bounds__(256) void ln_split_kernel(const float* __restrict__ x,
                                                       const float* __restrict__ sc,
                                                       const float* __restrict__ bi,
                                                       u16* __restrict__ oh,
                                                       u16* __restrict__ ol) {
    int row = blockIdx.x, tid = threadIdx.x;
    f32x4 u = *(const f32x4*)(x + (size_t)row * 1024 + tid * 4);
    float s = u[0] + u[1] + u[2] + u[3];
    float ss = u[0]*u[0] + u[1]*u[1] + u[2]*u[2] + u[3]*u[3];
    for (int off = 1; off < 64; off <<= 1) { s += __shfl_xor(s, off, 64); ss += __shfl_xor(ss, off, 64); }
    __shared__ float red[8];
    if ((tid & 63) == 0) { red[tid >> 6] = s; red[4 + (tid >> 6)] = ss; }
    __syncthreads();
    s = red[0] + red[1] + red[2] + red[3];
    ss = red[4] + red[5] + red[6] + red[7];
    float mu = s * (1.0f / 1024.0f);
    float rstd = rsqrtf(ss * (1.0f / 1024.0f) - mu * mu + 1e-5f);
    f32x4 g = *(const f32x4*)(sc + tid * 4);
    f32x4 b = *(const f32x4*)(bi + tid * 4);
    size_t o = (size_t)row * 1024 + tid * 4;
    for (int i = 0; i < 4; i++) {
        float v = (u[i] - mu) * rstd * g[i] + b[i];
        u16 hb = f2bf(v);
        oh[o + i] = hb;
        ol[o + i] = f2bf(v - bf2f(hb));
    }
}

// ------------- layernorm fp32 -> bf16 (MoE GEMM input) -------------
__global__ __launch_bounds__(256) void ln_f2b_kernel(const float* __restrict__ x,
                                                     const float* __restrict__ sc,
                                                     const float* __restrict__ bi,
                                                     u16* __restrict__ out) {
    int row = blockIdx.x, tid = threadIdx.x;
    f32x4 u = *(const f32x4*)(x + (size_t)row * 1024 + tid * 4);
    float s = u[0] + u[1] + u[2] + u[3];
    float ss = u[0]*u[0] + u[1]*u[1] + u[2]*u[2] + u[3]*u[3];
    for (int off = 1; off < 64; off <<= 1) { s += __shfl_xor(s, off, 64); ss += __shfl_xor(ss, off, 64); }
    __shared__ float red[8];
    if ((tid & 63) == 0) { red[tid >> 6] = s; red[4 + (tid >> 6)] = ss; }
    __syncthreads();
    s = red[0] + red[1] + red[2] + red[3];
    ss = red[4] + red[5] + red[6] + red[7];
    float mu = s * (1.0f / 1024.0f);
    float rstd = rsqrtf(ss * (1.0f / 1024.0f) - mu * mu + 1e-5f);
    f32x4 g = *(const f32x4*)(sc + tid * 4);
    f32x4 b = *(const f32x4*)(bi + tid * 4);
    u16* op = out + (size_t)row * 1024 + tid * 4;
    for (int i = 0; i < 4; i++)
        op[i] = f2bf((u[i] - mu) * rstd * g[i] + b[i]);
}

// ------------- fused QKV GEMM: glds staging + static epilogue --------------------------
__global__ __launch_bounds__(256) void gemm3_qkv(const u16* __restrict__ Ah_g,
                                                 const u16* __restrict__ Al_g,
                                                 const u16* __restrict__ Bh_g,
                                                 const u16* __restrict__ Bl_g,
                                                 u16* __restrict__ Ch, u16* __restrict__ Cl,
                                                 float scale) {
    const int K = 1024;
    __shared__ __align__(16) short Ahs[128 * 32], Als[128 * 32];
    __shared__ __align__(16) short Bhs[128 * 32], Bls[128 * 32];
    int m0 = blockIdx.y * 128, n0 = blockIdx.x * 128;
    int tid = threadIdx.x, lane = tid & 63, w = tid >> 6;
    int wm = (w & 1) * 64, wn = (w >> 1) * 64;
    int lr = lane & 15, lq = lane >> 4;
    int r0 = w * 32 + (lane >> 2);
    int cv = (lane & 3) * 8;
    const u16* pAh = Ah_g + (size_t)(m0 + r0) * K + cv;
    const u16* pAl = Al_g + (size_t)(m0 + r0) * K + cv;
    const u16* pBh = Bh_g + (size_t)(n0 + r0) * K + cv;
    const u16* pBl = Bl_g + (size_t)(n0 + r0) * K + cv;
    size_t st16 = (size_t)16 * K;
    f32x4 acc[4][4] = {};

    for (int k0 = 0; k0 < K; k0 += 32) {
        glds16(pAh + k0, &Ahs[w * 1024]);  glds16(pAh + k0 + st16, &Ahs[w * 1024 + 512]);
        glds16(pAl + k0, &Als[w * 1024]);  glds16(pAl + k0 + st16, &Als[w * 1024 + 512]);
        glds16(pBh + k0, &Bhs[w * 1024]);  glds16(pBh + k0 + st16, &Bhs[w * 1024 + 512]);
        glds16(pBl + k0, &Bls[w * 1024]);  glds16(pBl + k0 + st16, &Bls[w * 1024 + 512]);
        __syncthreads();   // barrier drains vmcnt: glds writes visible
        s16x8 ah[4], al[4], bh[4], bl[4];
        #pragma unroll
        for (int i = 0; i < 4; i++) {
            int off = (wm + i * 16 + lr) * 32 + lq * 8;
            ah[i] = *(const s16x8*)&Ahs[off];
            al[i] = *(const s16x8*)&Als[off];
        }
        #pragma unroll
        for (int j = 0; j < 4; j++) {
            int off = (wn + j * 16 + lr) * 32 + lq * 8;
            bh[j] = *(const s16x8*)&Bhs[off];
            bl[j] = *(const s16x8*)&Bls[off];
        }
        #pragma unroll
        for (int i = 0; i < 4; i++)
            #pragma unroll
            for (int j = 0; j < 4; j++) {
                acc[i][j] = __builtin_amdgcn_mfma_f32_16x16x32_bf16(al[i], bh[j], acc[i][j], 0, 0, 0);
                acc[i][j] = __builtin_amdgcn_mfma_f32_16x16x32_bf16(ah[i], bl[j], acc[i][j], 0, 0, 0);
                acc[i][j] = __builtin_amdgcn_mfma_f32_16x16x32_bf16(ah[i], bh[j], acc[i][j], 0, 0, 0);
            }
        __syncthreads();
    }

    int seg = n0 >> 10;
    float sc = (seg == 0) ? scale : 1.0f;
    u16* Chp = Ch + (size_t)seg * 8388608;
    u16* Clp = Cl + (size_t)seg * 8388608;
    int c0 = (n0 & 1023) + wn;
    #pragma unroll
    for (int i = 0; i < 4; i++)
        #pragma unroll
        for (int j = 0; j < 4; j++)
            #pragma unroll
            for (int r = 0; r < 4; r++) {
                int row = m0 + wm + i * 16 + lq * 4 + r;
                int col = c0 + j * 16 + lr;
                float vv = acc[i][j][r] * sc;
                u16 hb = f2bf(vv);
                u16 lb = f2bf(vv - bf2f(hb));
                size_t idx = (size_t)row * 1024 + col;
                Chp[idx] = hb; Clp[idx] = lb;
            }
}

// ------------- Wo GEMM: glds staging, fp32 C = A@B^T + res ----------------------------
__global__ __launch_bounds__(256) void gemm3_res(const u16* __restrict__ Ah_g,
                                                 const u16* __restrict__ Al_g,
                                                 const u16* __restrict__ Bh_g,
                                                 const u16* __restrict__ Bl_g,
                                                 float* __restrict__ C,
                                                 const float* __restrict__ res) {
    const int K = 1024, N = 1024;
    __shared__ __align__(16) short Ahs[128 * 32], Als[128 * 32];
    __shared__ __align__(16) short Bhs[128 * 32], Bls[128 * 32];
    int m0 = blockIdx.y * 128, n0 = blockIdx.x * 128;
    int tid = threadIdx.x, lane = tid & 63, w = tid >> 6;
    int wm = (w & 1) * 64, wn = (w >> 1) * 64;
    int lr = lane & 15, lq = lane >> 4;
    int r0 = w * 32 + (lane >> 2);
    int cv = (lane & 3) * 8;
    const u16* pAh = Ah_g + (size_t)(m0 + r0) * K + cv;
    const u16* pAl = Al_g + (size_t)(m0 + r0) * K + cv;
    const u16* pBh = Bh_g + (size_t)(n0 + r0) * K + cv;
    const u16* pBl = Bl_g + (size_t)(n0 + r0) * K + cv;
    size_t st16 = (size_t)16 * K;
    f32x4 acc[4][4] = {};

    for (int k0 = 0; k0 < K; k0 += 32) {
        glds16(pAh + k0, &Ahs[w * 1024]);  glds16(pAh + k0 + st16, &Ahs[w * 1024 + 512]);
        glds16(pAl + k0, &Als[w * 1024]);  glds16(pAl + k0 + st16, &Als[w * 1024 + 512]);
        glds16(pBh + k0, &Bhs[w * 1024]);  glds16(pBh + k0 + st16, &Bhs[w * 1024 + 512]);
        glds16(pBl + k0, &Bls[w * 1024]);  glds16(pBl + k0 + st16, &Bls[w * 1024 + 512]);
        __syncthreads();
        s16x8 ah[4], al[4], bh[4], bl[4];
        #pragma unroll
        for (int i = 0; i < 4; i++) {
            int off = (wm + i * 16 + lr) * 32 + lq * 8;
            ah[i] = *(const s16x8*)&Ahs[off];
            al[i] = *(const s16x8*)&Als[off];
        }
        #pragma unroll
        for (int j = 0; j < 4; j++) {
            int off = (wn + j * 16 + lr) * 32 + lq * 8;
            bh[j] = *(const s16x8*)&Bhs[off];
            bl[j] = *(const s16x8*)&Bls[off];
        }
        #pragma unroll
        for (int i = 0; i < 4; i++)
            #pragma unroll
            for (int j = 0; j < 4; j++) {
                acc[i][j] = __builtin_amdgcn_mfma_f32_16x16x32_bf16(al[i], bh[j], acc[i][j], 0, 0, 0);
                acc[i][j] = __builtin_amdgcn_mfma_f32_16x16x32_bf16(ah[i], bl[j], acc[i][j], 0, 0, 0);
                acc[i][j] = __builtin_amdgcn_mfma_f32_16x16x32_bf16(ah[i], bh[j], acc[i][j], 0, 0, 0);
            }
        __syncthreads();
    }

    #pragma unroll
    for (int i = 0; i < 4; i++)
        #pragma unroll
        for (int j = 0; j < 4; j++)
            #pragma unroll
            for (int r = 0; r < 4; r++) {
                int row = m0 + wm + i * 16 + lq * 4 + r;
                int col = n0 + wn + j * 16 + lr;
                size_t idx = (size_t)row * N + col;
                C[idx] = acc[i][j][r] + res[idx];
            }
}

// ------------- MoE up GEMM: dense, glds staging (round-9 measured-best config) --------
__global__ __launch_bounds__(256) void gemm_moe_up(const u16* __restrict__ A,
                                                   const u16* __restrict__ BT,
                                                   u16* __restrict__ C,
                                                   const float* __restrict__ gates) {
    const int K = 1024, N = 4096;
    __shared__ __align__(16) short As[128 * 32];
    __shared__ __align__(16) short Bs[128 * 32];
    int m0 = blockIdx.y * 128, n0 = blockIdx.x * 128;
    int tid = threadIdx.x, lane = tid & 63, w = tid >> 6;
    int wm = (w & 1) * 64, wn = (w >> 1) * 64;
    int lr = lane & 15, lq = lane >> 4;
    int r0 = w * 32 + (lane >> 2);
    int cv = (lane & 3) * 8;
    const u16* pA = A  + (size_t)(m0 + r0) * K + cv;
    const u16* pB = BT + (size_t)(n0 + r0) * K + cv;
    size_t st16 = (size_t)16 * K;
    f32x4 acc[4][4] = {};

    for (int k0 = 0; k0 < K; k0 += 32) {
        glds16(pA + k0, &As[w * 1024]);  glds16(pA + k0 + st16, &As[w * 1024 + 512]);
        glds16(pB + k0, &Bs[w * 1024]);  glds16(pB + k0 + st16, &Bs[w * 1024 + 512]);
        __syncthreads();
        s16x8 av[4], bv[4];
        #pragma unroll
        for (int i = 0; i < 4; i++) av[i] = *(const s16x8*)&As[(wm + i * 16 + lr) * 32 + lq * 8];
        #pragma unroll
        for (int j = 0; j < 4; j++) bv[j] = *(const s16x8*)&Bs[(wn + j * 16 + lr) * 32 + lq * 8];
        #pragma unroll
        for (int i = 0; i < 4; i++)
            #pragma unroll
            for (int j = 0; j < 4; j++)
                acc[i][j] = __builtin_amdgcn_mfma_f32_16x16x32_bf16(av[i], bv[j], acc[i][j], 0, 0, 0);
        __syncthreads();
    }

    #pragma unroll
    for (int i = 0; i < 4; i++)
        #pragma unroll
        for (int j = 0; j < 4; j++)
            #pragma unroll
            for (int r = 0; r < 4; r++) {
                int row = m0 + wm + i * 16 + lq * 4 + r;
                int col = n0 + wn + j * 16 + lr;
                float g = gates[(size_t)row * 16 + (col >> 8)];
                C[(size_t)row * N + col] = f2bf(fmaxf(acc[i][j][r], 0.0f) * g);
            }
}

// ------------- MoE down GEMM: dense, glds staging -------------------------------------
__global__ __launch_bounds__(256) void gemm_moe_down(const u16* __restrict__ A,
                                                     const u16* __restrict__ BT,
                                                     float* __restrict__ C,
                                                     const float* __restrict__ res) {
    const int K = 4096, N = 1024;
    __shared__ __align__(16) short As[128 * 32];
    __shared__ __align__(16) short Bs[128 * 32];
    int m0 = blockIdx.y * 128, n0 = blockIdx.x * 128;
    int tid = threadIdx.x, lane = tid & 63, w = tid >> 6;
    int wm = (w & 1) * 64, wn = (w >> 1) * 64;
    int lr = lane & 15, lq = lane >> 4;
    int r0 = w * 32 + (lane >> 2);
    int cv = (lane & 3) * 8;
    const u16* pA = A  + (size_t)(m0 + r0) * K + cv;
    const u16* pB = BT + (size_t)(n0 + r0) * K + cv;
    size_t st16 = (size_t)16 * K;
    f32x4 acc[4][4] = {};

    for (int k0 = 0; k0 < K; k0 += 32) {
        glds16(pA + k0, &As[w * 1024]);  glds16(pA + k0 + st16, &As[w * 1024 + 512]);
        glds16(pB + k0, &Bs[w * 1024]);  glds16(pB + k0 + st16, &Bs[w * 1024 + 512]);
        __syncthreads();
        s16x8 av[4], bv[4];
        #pragma unroll
        for (int i = 0; i < 4; i++) av[i] = *(const s16x8*)&As[(wm + i * 16 + lr) * 32 + lq * 8];
        #pragma unroll
        for (int j = 0; j < 4; j++) bv[j] = *(const s16x8*)&Bs[(wn + j * 16 + lr) * 32 + lq * 8];
        #pragma unroll
        for (int i = 0; i < 4; i++)
            #pragma unroll
            for (int j = 0; j < 4; j++)
                acc[i][j] = __builtin_amdgcn_mfma_f32_16x16x32_bf16(av[i], bv[j], acc[i][j], 0, 0, 0);
        __syncthreads();
    }

    #pragma unroll
    for (int i = 0; i < 4; i++)
        #pragma unroll
        for (int j = 0; j < 4; j++)
            #pragma unroll
            for (int r = 0; r < 4; r++) {
                int row = m0 + wm + i * 16 + lq * 4 + r;
                int col = n0 + wn + j * 16 + lr;
                size_t idx = (size_t)row * N + col;
                C[idx] = acc[i][j][r] + res[idx];
            }
}

// ------------- V transpose: v_hi/lo [4096][1024] -> vT_hi/lo [32 bh][64 d][2048 s] -------
__global__ __launch_bounds__(256) void vtrans_kernel(const u16* __restrict__ v_hi,
                                                     const u16* __restrict__ v_lo,
                                                     u16* __restrict__ vT_hi,
                                                     u16* __restrict__ vT_lo) {
    __shared__ __align__(16) short tile[64][72];
    int st = blockIdx.x, bh = blockIdx.y;
    int b = bh >> 4, h = bh & 15;
    int tid = threadIdx.x;
    int i = tid >> 2, seg = (tid & 3) * 16;
    for (int p = 0; p < 2; p++) {
        const u16* src = p ? v_lo : v_hi;
        u16* dst = p ? vT_lo : vT_hi;
        size_t goff = (size_t)(b * 2048 + st * 64 + i) * 1024 + h * 64 + seg;
        *(s16x8*)&tile[i][seg]     = *(const s16x8*)&src[goff];
        *(s16x8*)&tile[i][seg + 8] = *(const s16x8*)&src[goff + 8];
        __syncthreads();
        s16x8 o0, o1;
        for (int j = 0; j < 8; j++) { o0[j] = tile[seg + j][i]; o1[j] = tile[seg + 8 + j][i]; }
        size_t doff = ((size_t)bh * 64 + i) * 2048 + st * 64 + seg;
        *(s16x8*)&dst[doff]     = o0;
        *(s16x8*)&dst[doff + 8] = o1;
        __syncthreads();
    }
}

// ------------- MFMA flash attention, split-bf16 (3-term), online softmax -------------
// Round-9 structure (204.5us measured) with ONE change: the P hi/lo split uses
// v_cvt_pk_bf16_f32 (T12 primitive; RNE, bit-identical to f2bf for finite inputs)
// -- the split was ~384 of ~700 VALU insts/chunk/wave (VALUBusy 42% vs Mfma 22%);
// cvt_pk path is ~8 insts per value-pair vs ~24. Everything else byte-identical.
__global__ __launch_bounds__(256) void attn_mfma(const u16* __restrict__ qh_g,
                                                 const u16* __restrict__ ql_g,
                                                 const u16* __restrict__ kh_g,
                                                 const u16* __restrict__ kl_g,
                                                 const u16* __restrict__ vth_g,
                                                 const u16* __restrict__ vtl_g,
                                                 u16* __restrict__ ch_g,
                                                 u16* __restrict__ cl_g) {
    __shared__ __align__(16) short Ksh[64][72], Ksl[64][72], Vsh[64][72], Vsl[64][72];
    __shared__ __align__(16) short Ph[4][16 * 64], Pl[4][16 * 64];
    int lin = blockIdx.x + 16 * blockIdx.y;
    int xcd = lin & 7, rest = lin >> 3;
    int qt = rest & 15;
    int bh = xcd + 8 * (rest >> 4);
    int b = bh >> 4, h = bh & 15;
    int tid = threadIdx.x, w = tid >> 6, lane = tid & 63;
    int lr = lane & 15, lq = lane >> 4;
    int qbase = qt * 128 + w * 32;

    s16x8 qfh[2][2], qfl[2][2];
    for (int rt = 0; rt < 2; rt++)
        for (int kc = 0; kc < 2; kc++) {
            size_t qoff = (size_t)(b * 2048 + qbase + rt * 16 + lr) * 1024 + h * 64 + kc * 32 + lq * 8;
            qfh[rt][kc] = *(const s16x8*)&qh_g[qoff];
            qfl[rt][kc] = *(const s16x8*)&ql_g[qoff];
        }

    float m_[2][4], l_[2][4];
    f32x4 O[2][4] = {};
    for (int rt = 0; rt < 2; rt++)
        for (int r = 0; r < 4; r++) { m_[rt][r] = -1e30f; l_[rt][r] = 0.0f; }

    for (int kc0 = 0; kc0 < 2048; kc0 += 64) {
        {   // stage K chunk [key][d] and V^T chunk [d][key] (L2-hits after swizzle)
            int kk = tid >> 2, seg = (tid & 3) * 16;
            size_t goff = (size_t)(b * 2048 + kc0 + kk) * 1024 + h * 64 + seg;
            *(s16x8*)&Ksh[kk][seg]     = *(const s16x8*)&kh_g[goff];
            *(s16x8*)&Ksh[kk][seg + 8] = *(const s16x8*)&kh_g[goff + 8];
            *(s16x8*)&Ksl[kk][seg]     = *(const s16x8*)&kl_g[goff];
            *(s16x8*)&Ksl[kk][seg + 8] = *(const s16x8*)&kl_g[goff + 8];
            size_t voff = ((size_t)bh * 64 + kk) * 2048 + kc0 + seg;
            *(s16x8*)&Vsh[kk][seg]     = *(const s16x8*)&vth_g[voff];
            *(s16x8*)&Vsh[kk][seg + 8] = *(const s16x8*)&vth_g[voff + 8];
            *(s16x8*)&Vsl[kk][seg]     = *(const s16x8*)&vtl_g[voff];
            *(s16x8*)&Vsl[kk][seg + 8] = *(const s16x8*)&vtl_g[voff + 8];
        }
        __syncthreads();

        f32x4 s[2][4] = {};
        for (int ct = 0; ct < 4; ct++)
            for (int kc = 0; kc < 2; kc++) {
                s16x8 kbh = *(const s16x8*)&Ksh[ct * 16 + lr][kc * 32 + lq * 8];
                s16x8 kbl = *(const s16x8*)&Ksl[ct * 16 + lr][kc * 32 + lq * 8];
                for (int rt = 0; rt < 2; rt++) {
                    s[rt][ct] = __builtin_amdgcn_mfma_f32_16x16x32_bf16(qfl[rt][kc], kbh, s[rt][ct], 0, 0, 0);
                    s[rt][ct] = __builtin_amdgcn_mfma_f32_16x16x32_bf16(qfh[rt][kc], kbl, s[rt][ct], 0, 0, 0);
                    s[rt][ct] = __builtin_amdgcn_mfma_f32_16x16x32_bf16(qfh[rt][kc], kbh, s[rt][ct], 0, 0, 0);
                }
            }

        for (int rt = 0; rt < 2; rt++) {
            float al[4];
            for (int ri = 0; ri < 4; ri++) {
                float mx = fmaxf(fmaxf(s[rt][0][ri], s[rt][1][ri]), fmaxf(s[rt][2][ri], s[rt][3][ri]));
                for (int off = 1; off < 16; off <<= 1) mx = fmaxf(mx, __shfl_xor(mx, off, 64));
                float mn = fmaxf(m_[rt][ri], mx);
                float a = __expf(m_[rt][ri] - mn);
                m_[rt][ri] = mn; al[ri] = a;
                float ps = 0.0f;
                for (int ct = 0; ct < 4; ct++) {
                    float p = __expf(s[rt][ct][ri] - mn);
                    s[rt][ct][ri] = p; ps += p;
                }
                for (int off = 1; off < 16; off <<= 1) ps += __shfl_xor(ps, off, 64);
                l_[rt][ri] = l_[rt][ri] * a + ps;
            }
            for (int nt = 0; nt < 4; nt++)
                for (int ri = 0; ri < 4; ri++) O[rt][nt][ri] *= al[ri];
            // split P (RNE) via v_cvt_pk_bf16_f32, per f32x4 value-pairs (ri 0/1, 2/3).
            // hi = cvt_pk(p0,p1); lo_k = p_k - bf2f(hi_k) (unpack via shl/and);
            // lo = cvt_pk(l0,l1). Bit-identical to the scalar f2bf path (both RNE).
            #pragma unroll
            for (int ct = 0; ct < 4; ct++)
                #pragma unroll
                for (int rp = 0; rp < 2; rp++) {
                    float p0 = s[rt][ct][2 * rp], p1 = s[rt][ct][2 * rp + 1];
                    unsigned int hpk, lpk;
                    asm("v_cvt_pk_bf16_f32 %0, %1, %2" : "=v"(hpk) : "v"(p0), "v"(p1));
                    union { unsigned int u; float f; } h0, h1;
                    h0.u = hpk << 16;
                    h1.u = hpk & 0xffff0000u;
                    float l0 = p0 - h0.f, l1 = p1 - h1.f;
                    asm("v_cvt_pk_bf16_f32 %0, %1, %2" : "=v"(lpk) : "v"(l0), "v"(l1));
                    int row0 = lq * 4 + 2 * rp, col = ct * 16 + lr;
                    int i0 = (row0 * 64 + col) ^ ((row0 & 7) << 3);
                    int i1 = ((row0 + 1) * 64 + col) ^ (((row0 + 1) & 7) << 3);
                    Ph[w][i0] = (short)(hpk & 0xffffu);
                    Ph[w][i1] = (short)(hpk >> 16);
                    Pl[w][i0] = (short)(lpk & 0xffffu);
                    Pl[w][i1] = (short)(lpk >> 16);
                }
            asm volatile("s_waitcnt lgkmcnt(0)" ::: "memory");
            __builtin_amdgcn_sched_barrier(0);
            __builtin_amdgcn_s_setprio(1);
            for (int kc = 0; kc < 2; kc++) {
                int pidx = (lr * 64 + kc * 32 + lq * 8) ^ ((lr & 7) << 3);
                s16x8 pah = *(const s16x8*)&Ph[w][pidx];
                s16x8 pal = *(const s16x8*)&Pl[w][pidx];
                for (int nt = 0; nt < 4; nt++) {
                    s16x8 vbh = *(const s16x8*)&Vsh[nt * 16 + lr][kc * 32 + lq * 8];
                    s16x8 vbl = *(const s16x8*)&Vsl[nt * 16 + lr][kc * 32 + lq * 8];
                    O[rt][nt] = __builtin_amdgcn_mfma_f32_16x16x32_bf16(pal, vbh, O[rt][nt], 0, 0, 0);
                    O[rt][nt] = __builtin_amdgcn_mfma_f32_16x16x32_bf16(pah, vbl, O[rt][nt], 0, 0, 0);
                    O[rt][nt] = __builtin_amdgcn_mfma_f32_16x16x32_bf16(pah, vbh, O[rt][nt], 0, 0, 0);
                }
            }
            __builtin_amdgcn_s_setprio(0);
            asm volatile("s_waitcnt lgkmcnt(0)" ::: "memory");
            __builtin_amdgcn_sched_barrier(0);
        }
        __syncthreads();
    }

    for (int rt = 0; rt < 2; rt++)
        for (int nt = 0; nt < 4; nt++)
            for (int ri = 0; ri < 4; ri++) {
                int row = qbase + rt * 16 + lq * 4 + ri;
                int d = nt * 16 + lr;
                float v = O[rt][nt][ri] / l_[rt][ri];
                u16 hb = f2bf(v);
                size_t idx = (size_t)(b * 2048 + row) * 1024 + h * 64 + d;
                ch_g[idx] = hb;
                cl_g[idx] = f2bf(v - bf2f(hb));
            }
}

// ------------- router: pure fp32 (decisions must match fp32 reference) -------------
__global__ __launch_bounds__(256) void router_kernel(const float* __restrict__ x2,
                                                     const float* __restrict__ sc,
                                                     const float* __restrict__ bi,
                                                     const float* __restrict__ Wsel,
                                                     float* __restrict__ gates) {
    int tid = threadIdx.x, w = tid >> 6, lane = tid & 63;
    int t = blockIdx.x * 4 + w;
    const float* xp = x2 + (size_t)t * 1024;
    float s = 0.0f, ss = 0.0f;
    for (int i = 0; i < 16; i++) {
        float v = xp[lane * 16 + i];
        s += v; ss += v * v;
    }
    for (int off = 1; off < 64; off <<= 1) { s += __shfl_xor(s, off, 64); ss += __shfl_xor(ss, off, 64); }
    float mu = s * (1.0f / 1024.0f);
    float rstd = rsqrtf(ss * (1.0f / 1024.0f) - mu * mu + 1e-5f);
    int e = lane & 15, part = lane >> 4;
    float acc = 0.0f;
    for (int d = part * 256; d < part * 256 + 256; d++) {
        float h = (xp[d] - mu) * rstd * sc[d] + bi[d];
        acc += h * Wsel[(size_t)d * 16 + e];
    }
    acc += __shfl_xor(acc, 16, 64);
    acc += __shfl_xor(acc, 32, 64);
    float v = 1.0f / (1.0f + __expf(-acc));
    float m1 = v;
    for (int off = 1; off < 64; off <<= 1) m1 = fmaxf(m1, __shfl_xor(m1, off, 64));
    unsigned long long b1 = __ballot(v == m1);
    int e1 = (__ffsll(b1) - 1) & 15;
    float v2 = (e == e1) ? -1e30f : v;
    float m2 = v2;
    for (int off = 1; off < 64; off <<= 1) m2 = fmaxf(m2, __shfl_xor(m2, off, 64));
    unsigned long long b2 = __ballot(v2 == m2);
    int e2 = (__ffsll(b2) - 1) & 15;
    if (lane < 16)
        gates[(size_t)t * 16 + e] = (e == e1) ? m1 : (e == e2 ? m2 : 0.0f);
}

extern "C" void kernel_launch(void* const* d_in, const int* in_sizes, int n_in,
                              void* d_out, int out_size, void* d_ws, size_t ws_size,
                              hipStream_t stream) {
    const float* x    = (const float*)d_in[0];
    const float* Wq   = (const float*)d_in[1];
    const float* Wk   = (const float*)d_in[2];
    const float* Wv   = (const float*)d_in[3];
    const float* Wo   = (const float*)d_in[4];
    const float* ln1s = (const float*)d_in[5];
    const float* ln1b = (const float*)d_in[6];
    const float* ln2s = (const float*)d_in[7];
    const float* ln2b = (const float*)d_in[8];
    const float* Wsel = (const float*)d_in[9];
    const float* W1   = (const float*)d_in[10];
    const float* W2   = (const float*)d_in[11];
    float* out = (float*)d_out;

    // Workspace (96 MB total, liveness-overlaid) -- round-9 layout:
    //  [0,8)   h1_hi bf16 -> vT_hi -> h2 bf16
    //  [8,16)  h1_lo bf16 -> vT_lo -> gates (64 KB)
    //  [16,48) q_hi/q_lo/k_hi/k_lo bf16 -> up bf16 after attn
    //  [48,64) v_hi/v_lo bf16 -> ctx_hi/ctx_lo bf16 after vtrans
    //  [64,80) x2 fp32 (live to end)
    //  [80,96) Wqkv hi [80,86) + lo [86,92) + WoT h/l -> W1T [80,88) + W2T [88,96)
    char* ws = (char*)d_ws;
    const size_t MB = 1024 * 1024;
    u16*   h1_h  = (u16*)  (ws + 0 * MB);
    u16*   h1_l  = (u16*)  (ws + 8 * MB);
    u16*   vT_hi = (u16*)  (ws + 0 * MB);
    u16*   vT_lo = (u16*)  (ws + 8 * MB);
    u16*   h2    = (u16*)  (ws + 0 * MB);
    float* gates = (float*)(ws + 8 * MB);
    u16*   q_hi  = (u16*)  (ws + 16 * MB);
    u16*   q_lo  = (u16*)  (ws + 24 * MB);
    u16*   k_hi  = (u16*)  (ws + 32 * MB);
    u16*   k_lo  = (u16*)  (ws + 40 * MB);
    u16*   up    = (u16*)  (ws + 16 * MB);
    u16*   v_hi  = (u16*)  (ws + 48 * MB);
    u16*   v_lo  = (u16*)  (ws + 56 * MB);
    u16*   ctx_h = (u16*)  (ws + 48 * MB);
    u16*   ctx_l = (u16*)  (ws + 56 * MB);
    float* x2    = (float*)(ws + 64 * MB);
    u16*   WqT_h = (u16*)  (ws + 80 * MB);   // [80,86): WqT_h | WkT_h | WvT_h = [3072][1024]
    u16*   WkT_h = (u16*)  (ws + 82 * MB);
    u16*   WvT_h = (u16*)  (ws + 84 * MB);
    u16*   WqT_l = (u16*)  (ws + 86 * MB);   // [86,92): lo parts, same order
    u16*   WkT_l = (u16*)  (ws + 88 * MB);
    u16*   WvT_l = (u16*)  (ws + 90 * MB);
    u16*   WoT_h = (u16*)  (ws + 92 * MB);
    u16*   WoT_l = (u16*)  (ws + 94 * MB);
    u16*   W1T   = (u16*)  (ws + 80 * MB);
    u16*   W2T   = (u16*)  (ws + 88 * MB);

    // weight transposes + one-time hi/lo splits
    transpose_split_kernel<<<dim3(32, 32), 256, 0, stream>>>(Wq, WqT_h, WqT_l, 1024, 1024);
    transpose_split_kernel<<<dim3(32, 32), 256, 0, stream>>>(Wk, WkT_h, WkT_l, 1024, 1024);
    transpose_split_kernel<<<dim3(32, 32), 256, 0, stream>>>(Wv, WvT_h, WvT_l, 1024, 1024);
    transpose_split_kernel<<<dim3(32, 32), 256, 0, stream>>>(Wo, WoT_h, WoT_l, 1024, 1024);

    // LN1 -> h1 hi/lo bf16 (split once)
    ln_split_kernel<<<4096, 256, 0, stream>>>(x, ln1s, ln1b, h1_h, h1_l);
    // fused QKV projection (N=3072, 3 blocks/CU) -> bf16 hi/lo splits (Q pre-scaled 1/8)
    gemm3_qkv<<<dim3(24, 32), 256, 0, stream>>>(h1_h, h1_l, WqT_h, WqT_l, q_hi, q_lo, 0.125f);
    // V -> V^T per (b,h)
    vtrans_kernel<<<dim3(32, 32), 256, 0, stream>>>(v_hi, v_lo, vT_hi, vT_lo);
    // MFMA flash attention -> ctx hi/lo bf16
    attn_mfma<<<dim3(16, 32), 256, 0, stream>>>(q_hi, q_lo, k_hi, k_lo, vT_hi, vT_lo, ctx_h, ctx_l);
    // output projection + residual -> x2 fp32
    gemm3_res<<<dim3(8, 32), 256, 0, stream>>>(ctx_h, ctx_l, WoT_h, WoT_l, x2, x);
    // LN2 -> h2 bf16
    ln_f2b_kernel<<<4096, 256, 0, stream>>>(x2, ln2s, ln2b, h2);
    // router -> gates
    router_kernel<<<1024, 256, 0, stream>>>(x2, ln2s, ln2b, Wsel, gates);
    // MoE weight pre-transposes to bf16 [N][K] (after last WqkvT/WoT use; reuse [80,96))
    transpose_f2b_kernel<<<dim3(8, 32, 16), 256, 0, stream>>>(W1, W1T, 1024, 256);
    transpose_f2b_kernel<<<dim3(32, 128, 1), 256, 0, stream>>>(W2, W2T, 4096, 1024);
    // MoE up (dense, relu*gate) -> up bf16
    gemm_moe_up<<<dim3(32, 32), 256, 0, stream>>>(h2, W1T, up, gates);
    // MoE down + residual -> out fp32
    gemm_moe_down<<<dim3(8, 32), 256, 0, stream>>>(up, W2T, out, x2);
}